// Round 9
// baseline (576.553 us; speedup 1.0000x reference)
//
#include <hip/hip_runtime.h>
#include <hip/hip_bf16.h>

// PointerNetwork: B=4096, L=10, IN=8, H=512, W=512. fp32 in/out, ws=256MiB.
// log_softmax over size-1 axes => hi==he==0. Surviving compute:
//   enc GRU, ew3 = h_enc @ w3^T, dec GRU, a4 = h_dec @ w4^T,
//   out_seq = tanh(ew3+a4)@v2, out_ori = h_dec @ wori[:,H:2H]^T + bori.
// Round 15: gru_fused deep-restructure (the ~19us/step plateau):
//  - B operand straight to REGISTERS via W2 pre-rearranged weights
//    [g][c16][kb][hh][lane][16B]: every fragment load = one wave-contiguous
//    1KB transaction (fixes R7's 1KB-stride uncoalesced failure); no B LDS.
//  - A-only LDS, TRIPLE buffer (12KB), 2-deep prefetch, ONE barrier/iter:
//    {loadB(k+1); vmcnt(8); barrier; stageA(k+2); mfma} - FIFO-verified.
//  - 32x32 tile, 128 thr (2 waves), grid 2048, row-panel XCD swizzle
//    (by=flat&127, bx=flat>>7) -> 6-8 blocks/CU hide stalls.
// Rest = R8 proven (merged epi GEMM, out_seq contiguous-quarter, bf16 h).

#define B_   4096
#define L_   10
#define IN_  8
#define H_   512
#define H3_  1536
#define W_   512
#define ORI_BASE (B_ * L_ * L_)   // 409600

typedef __attribute__((ext_vector_type(8))) short s8v;
typedef __attribute__((ext_vector_type(4))) short s4v;
typedef __attribute__((ext_vector_type(4))) float f4v;

#define LOG2E  1.4426950408889634f
#define LOG2E2 2.8853900817779268f

__device__ __forceinline__ float sig_fast(float x) {
  float e = __builtin_amdgcn_exp2f(-x * LOG2E);
  return __builtin_amdgcn_rcpf(1.f + e);
}
__device__ __forceinline__ float tanh_fast(float x) {
  float e = __builtin_amdgcn_exp2f(x * LOG2E2);
  return 1.f - 2.f * __builtin_amdgcn_rcpf(e + 1.f);
}
__device__ __forceinline__ short f2bf(float f) {
  __hip_bfloat16 h = __float2bfloat16(f);
  return __builtin_bit_cast(short, h);
}
__device__ __forceinline__ float bf2f(short s) {
  __hip_bfloat16 h = __builtin_bit_cast(__hip_bfloat16, s);
  return __bfloat162float(h);
}
__device__ __forceinline__ void stc(float* p, float v) { *p = v; }
__device__ __forceinline__ void stc(short* p, float v) { *p = f2bf(v); }

// ---- fused prep: fp32->bf16 conversions in one dispatch (4 segments) ----
__global__ __launch_bounds__(256) void prep_all(
    const float* __restrict__ s2, short* __restrict__ d2,   // dec_wih 786432
    const float* __restrict__ s3, short* __restrict__ d3,   // w3      262144
    const float* __restrict__ s4, short* __restrict__ d4,   // w4      262144
    const float* __restrict__ s5, short* __restrict__ d5)   // dec_in  2097152
{
  long i8 = (long)blockIdx.x * 256 + threadIdx.x;   // unit = 8 elements
  const float* s; short* d; long off;
  if      (i8 < 98304)  { s = s2; d = d2; off = i8; }
  else if (i8 < 131072) { s = s3; d = d3; off = i8 - 98304; }
  else if (i8 < 163840) { s = s4; d = d4; off = i8 - 131072; }
  else if (i8 < 425984) { s = s5; d = d5; off = i8 - 163840; }
  else return;
  const float* sp = s + off * 8;
  s8v v;
#pragma unroll
  for (int j = 0; j < 8; ++j) v[j] = f2bf(sp[j]);
  *(s8v*)(d + off * 8) = v;
}

// ---- W2 weight rearrange for register-B gru:
// W2[g][c16][kb][hh][lane][8] bf16; lane=(r16,q): element =
// whh[g*512 + c16*16 + r16][kb*64 + hh*32 + q*8 + e]. One 16B chunk/thread.
__global__ __launch_bounds__(256) void prep_w2(
    const float* __restrict__ enc_whh, const float* __restrict__ dec_whh,
    short* __restrict__ W2e, short* __restrict__ W2d)
{
  int tg = blockIdx.x * 256 + threadIdx.x;  // 0..196607
  const float* src = enc_whh; short* dst = W2e;
  int t = tg;
  if (t >= 98304) { t -= 98304; src = dec_whh; dst = W2d; }
  int l = t & 63;
  int u = t >> 6;
  int hh = u & 1, kb = (u >> 1) & 7, c16 = (u >> 4) & 31, g = u >> 9;
  int row = g * 512 + c16 * 16 + (l & 15);
  int colb = kb * 64 + hh * 32 + (l >> 4) * 8;
  const float* sp = src + (long)row * 512 + colb;
  s8v v;
#pragma unroll
  for (int j = 0; j < 8; ++j) v[j] = f2bf(sp[j]);
  *(s8v*)(dst + (long)t * 8) = v;
}

// Fold embedding into encoder input weight. One wave per g-row (1536 waves).
__global__ __launch_bounds__(256) void build_wc(
    const float* __restrict__ enc_wih, const float* __restrict__ emb_w,
    const float* __restrict__ emb_b, const float* __restrict__ enc_bih,
    float* __restrict__ Wc, float* __restrict__ bc)
{
  __shared__ float se[H_ * IN_];   // 16 KB
  __shared__ float sb[H_];         // 2 KB
  const int tid = threadIdx.x;
  for (int i = tid; i < H_ * IN_; i += 256) se[i] = emb_w[i];
  for (int i = tid; i < H_; i += 256) sb[i] = emb_b[i];
  __syncthreads();
  int g = (blockIdx.x * 256 + tid) >> 6;
  int lane = tid & 63;
  const float* wr = enc_wih + (long)g * H_ + lane * 8;
  float w8[8];
#pragma unroll
  for (int j = 0; j < 8; ++j) w8[j] = wr[j];
  float acc[9] = {};
#pragma unroll
  for (int kk = 0; kk < 8; ++kk) {
    int k = lane * 8 + kk;
#pragma unroll
    for (int j = 0; j < 8; ++j) acc[j] += w8[kk] * se[k * IN_ + j];
    acc[8] += w8[kk] * sb[k];
  }
#pragma unroll
  for (int j = 0; j < 9; ++j)
#pragma unroll
    for (int off = 32; off; off >>= 1) acc[j] += __shfl_down(acc[j], off, 64);
  if (lane == 0) {
#pragma unroll
    for (int j = 0; j < 8; ++j) Wc[g * IN_ + j] = acc[j];
    bc[g] = acc[8] + enc_bih[g];
  }
}

// ---- Pipelined bf16 MFMA GEMM: C[M,N] = (A@B^T (+bias))*scale.
// 128x128 tile, BK=64, dbuf LDS, counted vmcnt(8), XOR-swizzle, setprio.
template <typename CT>
__global__ __launch_bounds__(256) void gemm_bf16(
    const short* __restrict__ A, long lda,
    const short* __restrict__ Bw, long ldb,
    const float* __restrict__ bias,
    CT* __restrict__ C, long ldc, int K, float scale)
{
  __shared__ short As[2][128 * 64];   // 32 KB
  __shared__ short Bs[2][128 * 64];   // 32 KB
  const int tid = threadIdx.x;
  const long row0 = (long)blockIdx.y * 128;
  const long col0 = (long)blockIdx.x * 128;
  const int wave = tid >> 6, lane = tid & 63;
  const int wm = (wave & 1) * 64, wn = (wave >> 1) * 64;
  const int r16 = lane & 15, quad = lane >> 4;
  const int sw = r16 & 7;
  f4v acc[4][4] = {};

  auto stage = [&](int buf, int k0) {
#pragma unroll
    for (int r = 0; r < 4; ++r) {             // A: 128x64 = 1024 chunks
      int idx = r * 256 + tid;
      int m = idx >> 3, c8 = idx & 7;
      int src = c8 ^ (m & 7);
      __builtin_amdgcn_global_load_lds(
          (const __attribute__((address_space(1))) void*)(A + (row0 + m) * lda + k0 + src * 8),
          (__attribute__((address_space(3))) void*)(&As[buf][idx * 8]), 16, 0, 0);
    }
#pragma unroll
    for (int r = 0; r < 4; ++r) {             // B: 128x64 = 1024 chunks
      int idx = r * 256 + tid;
      int m = idx >> 3, c8 = idx & 7;
      int src = c8 ^ (m & 7);
      __builtin_amdgcn_global_load_lds(
          (const __attribute__((address_space(1))) void*)(Bw + (col0 + m) * ldb + k0 + src * 8),
          (__attribute__((address_space(3))) void*)(&Bs[buf][idx * 8]), 16, 0, 0);
    }
  };

  const int nk = K >> 6;
  stage(0, 0);
  for (int k = 0; k < nk; ++k) {
    if (k < nk - 1) {
      stage((k + 1) & 1, (k + 1) * 64);
      asm volatile("s_waitcnt vmcnt(8)" ::: "memory");   // cur's 8 loads done
    } else {
      asm volatile("s_waitcnt vmcnt(0)" ::: "memory");
    }
    __builtin_amdgcn_s_barrier();
    const short* Asc = As[k & 1];
    const short* Bsc = Bs[k & 1];
    s8v af[4][2], bf[4][2];
#pragma unroll
    for (int i = 0; i < 4; ++i)
#pragma unroll
      for (int hh = 0; hh < 2; ++hh)
        af[i][hh] = *(const s8v*)&Asc[(wm + i * 16 + r16) * 64 + ((hh * 4 + quad) ^ sw) * 8];
#pragma unroll
    for (int j = 0; j < 4; ++j)
#pragma unroll
      for (int hh = 0; hh < 2; ++hh)
        bf[j][hh] = *(const s8v*)&Bsc[(wn + j * 16 + r16) * 64 + ((hh * 4 + quad) ^ sw) * 8];
    __builtin_amdgcn_s_setprio(1);
#pragma unroll
    for (int hh = 0; hh < 2; ++hh)
#pragma unroll
      for (int i = 0; i < 4; ++i)
#pragma unroll
        for (int j = 0; j < 4; ++j)
          acc[i][j] = __builtin_amdgcn_mfma_f32_16x16x32_bf16(af[i][hh], bf[j][hh], acc[i][j], 0, 0, 0);
    __builtin_amdgcn_s_setprio(0);
    __builtin_amdgcn_s_barrier();
  }

#pragma unroll
  for (int i = 0; i < 4; ++i) {
    long rbase = row0 + wm + i * 16 + quad * 4;
#pragma unroll
    for (int j = 0; j < 4; ++j) {
      long c = col0 + wn + j * 16 + r16;
      float bv = bias ? bias[c] : 0.f;
#pragma unroll
      for (int rg = 0; rg < 4; ++rg)
        stc(&C[(rbase + rg) * ldc + c], (acc[i][j][rg] + bv) * scale);
    }
  }
}

// ---- Merged epilogue GEMM: z=0 -> ew3 = enc_hist@w3^T; z=1 -> a4 =
// dec_hist@w4^T. Same pipelined body, output *LOG2E2 as bf16.
__global__ __launch_bounds__(256) void gemm_epi(
    const short* __restrict__ Ae, const short* __restrict__ Ad,
    const short* __restrict__ w3b, const short* __restrict__ w4b,
    short* __restrict__ Ce, short* __restrict__ Cd)
{
  const short* A  = blockIdx.z ? Ad : Ae;
  const short* Bw = blockIdx.z ? w4b : w3b;
  short* C        = blockIdx.z ? Cd : Ce;
  __shared__ short As[2][128 * 64];
  __shared__ short Bs[2][128 * 64];
  const int tid = threadIdx.x;
  const long row0 = (long)blockIdx.y * 128;
  const long col0 = (long)blockIdx.x * 128;
  const int wave = tid >> 6, lane = tid & 63;
  const int wm = (wave & 1) * 64, wn = (wave >> 1) * 64;
  const int r16 = lane & 15, quad = lane >> 4;
  const int sw = r16 & 7;
  f4v acc[4][4] = {};

  auto stage = [&](int buf, int k0) {
#pragma unroll
    for (int r = 0; r < 4; ++r) {
      int idx = r * 256 + tid;
      int m = idx >> 3, c8 = idx & 7;
      int src = c8 ^ (m & 7);
      __builtin_amdgcn_global_load_lds(
          (const __attribute__((address_space(1))) void*)(A + (row0 + m) * H_ + k0 + src * 8),
          (__attribute__((address_space(3))) void*)(&As[buf][idx * 8]), 16, 0, 0);
    }
#pragma unroll
    for (int r = 0; r < 4; ++r) {
      int idx = r * 256 + tid;
      int m = idx >> 3, c8 = idx & 7;
      int src = c8 ^ (m & 7);
      __builtin_amdgcn_global_load_lds(
          (const __attribute__((address_space(1))) void*)(Bw + (col0 + m) * H_ + k0 + src * 8),
          (__attribute__((address_space(3))) void*)(&Bs[buf][idx * 8]), 16, 0, 0);
    }
  };

  stage(0, 0);
  for (int k = 0; k < 8; ++k) {
    if (k < 7) {
      stage((k + 1) & 1, (k + 1) * 64);
      asm volatile("s_waitcnt vmcnt(8)" ::: "memory");
    } else {
      asm volatile("s_waitcnt vmcnt(0)" ::: "memory");
    }
    __builtin_amdgcn_s_barrier();
    const short* Asc = As[k & 1];
    const short* Bsc = Bs[k & 1];
    s8v af[4][2], bf[4][2];
#pragma unroll
    for (int i = 0; i < 4; ++i)
#pragma unroll
      for (int hh = 0; hh < 2; ++hh)
        af[i][hh] = *(const s8v*)&Asc[(wm + i * 16 + r16) * 64 + ((hh * 4 + quad) ^ sw) * 8];
#pragma unroll
    for (int j = 0; j < 4; ++j)
#pragma unroll
      for (int hh = 0; hh < 2; ++hh)
        bf[j][hh] = *(const s8v*)&Bsc[(wn + j * 16 + r16) * 64 + ((hh * 4 + quad) ^ sw) * 8];
    __builtin_amdgcn_s_setprio(1);
#pragma unroll
    for (int hh = 0; hh < 2; ++hh)
#pragma unroll
      for (int i = 0; i < 4; ++i)
#pragma unroll
        for (int j = 0; j < 4; ++j)
          acc[i][j] = __builtin_amdgcn_mfma_f32_16x16x32_bf16(af[i][hh], bf[j][hh], acc[i][j], 0, 0, 0);
    __builtin_amdgcn_s_setprio(0);
    __builtin_amdgcn_s_barrier();
  }

#pragma unroll
  for (int i = 0; i < 4; ++i) {
    long rbase = row0 + wm + i * 16 + quad * 4;
#pragma unroll
    for (int j = 0; j < 4; ++j) {
      long c = col0 + wn + j * 16 + r16;
#pragma unroll
      for (int rg = 0; rg < 4; ++rg)
        C[(rbase + rg) * W_ + c] = f2bf(acc[i][j][rg] * LOG2E2);
    }
  }
}

// ---- Fused GRU step, Round-15 structure.
// 32 rows x 32 cols x 3 gates per block; 128 thr (2 waves, wave wv owns cols
// [col0+wv*16,+16)); grid 2048 (by=flat&127 row panel, bx=flat>>7 col block;
// flat%8=by%8 -> row-panel sharers same-XCD). A in LDS TRIPLE buffer (12KB),
// B from W2 in registers (coalesced 1KB wave loads). Per iter: {loadB(k+1);
// vmcnt(8); barrier; stageA(k+2); mfma} - one barrier, 2-deep A prefetch.
template <bool ENC>
__global__ __launch_bounds__(128) void gru_fused(
    const short* __restrict__ Aprev,  // (B,H) bf16 h_{t-1}
    const short* __restrict__ W2,     // rearranged weights (prep_w2)
    const float* __restrict__ bhh,    // (3H)
    const short* __restrict__ xg,     // (B,3H) bf16 (decoder)
    const float* __restrict__ items_t,// encoder: &items[0][t][0], row stride 80
    const float* __restrict__ Wc,     // (3H,8)
    const float* __restrict__ bc,     // (3H)
    short* __restrict__ hout)         // (B,H) bf16 history slice
{
  __shared__ short As3[3][32 * 64];   // 12 KB
  const int tid = threadIdx.x;
  const int flat = blockIdx.x;
  const int by = flat & 127, bx = flat >> 7;
  const long row0 = (long)by * 32;
  const int col0 = bx * 32;
  const int wv = tid >> 6, lane = tid & 63;
  const int r16 = lane & 15, quad = lane >> 4;
  const int sw = r16 & 7;
  const int c16 = bx * 2 + wv;
  const int col = col0 + wv * 16 + r16;

  f4v acc[3][2] = {};   // [gate][frag-row]
  s8v bfr[2][3][2];     // register B double-buffer

  auto stageA = [&](int buf, int k0i) {
#pragma unroll
    for (int r = 0; r < 2; ++r) {             // A: 32x64 = 256 chunks
      int idx = r * 128 + tid;
      int m = idx >> 3, c8 = idx & 7;
      int src = c8 ^ (m & 7);
      __builtin_amdgcn_global_load_lds(
          (const __attribute__((address_space(1))) void*)(Aprev + (row0 + m) * H_ + k0i * 64 + src * 8),
          (__attribute__((address_space(3))) void*)(&As3[buf][idx * 8]), 16, 0, 0);
    }
  };
  auto loadB = [&](s8v (&dst)[3][2], int kb) {
#pragma unroll
    for (int g = 0; g < 3; ++g)
#pragma unroll
      for (int hh = 0; hh < 2; ++hh)
        dst[g][hh] = *(const s8v*)(W2 + ((((long)(g * 32 + c16) * 8 + kb) * 2 + hh) * 512) + lane * 8);
  };

  // prologue FIFO: A0(2), B0(6), A1(2)  -> 10 outstanding
  stageA(0, 0);
  loadB(bfr[0], 0);
  stageA(1, 1);
#pragma unroll
  for (int k = 0; k < 8; ++k) {
    if (k < 7) {
      loadB(bfr[(k + 1) & 1], k + 1);     // +6 -> 16 outstanding
      asm volatile("s_waitcnt vmcnt(8)" ::: "memory");   // retire A(k),B(k)
    } else {
      asm volatile("s_waitcnt vmcnt(0)" ::: "memory");
    }
    __builtin_amdgcn_s_barrier();          // A(k) published; k-1 reads done
    if (k < 6) stageA((k + 2) % 3, k + 2); // safe: buf (k+2)%3 = (k-1)%3 free
    s8v af[2][2];
#pragma unroll
    for (int i = 0; i < 2; ++i)
#pragma unroll
      for (int hh = 0; hh < 2; ++hh)
        af[i][hh] = *(const s8v*)&As3[k % 3][(i * 16 + r16) * 64 + ((hh * 4 + quad) ^ sw) * 8];
    __builtin_amdgcn_s_setprio(1);
#pragma unroll
    for (int hh = 0; hh < 2; ++hh)
#pragma unroll
      for (int g = 0; g < 3; ++g)
#pragma unroll
        for (int i = 0; i < 2; ++i)
          acc[g][i] = __builtin_amdgcn_mfma_f32_16x16x32_bf16(af[i][hh], bfr[k & 1][g][hh], acc[g][i], 0, 0, 0);
    __builtin_amdgcn_s_setprio(0);
  }

  // Column owned by this thread (C/D layout: col=lane&15, row=quad*4+reg).
  float wc[3][8], bcv[3];
  if (ENC) {
#pragma unroll
    for (int g = 0; g < 3; ++g) {
      const float* wr = Wc + ((long)g * H_ + col) * IN_;
#pragma unroll
      for (int j = 0; j < 8; ++j) wc[g][j] = wr[j];
      bcv[g] = bc[g * H_ + col];
    }
    // stage items rows into LDS (reuse As3 buf0; iter-7 read buf1 - safe):
    // 32 rows x 8 fp32 = 256 f32, 128 threads x 2
    float* itemS = (float*)As3;
    int i2 = tid * 2;
    int m = i2 >> 3, j = i2 & 7;
    itemS[i2] = items_t[(row0 + m) * (L_ * IN_) + j];
    itemS[i2 + 1] = items_t[(row0 + m) * (L_ * IN_) + j + 1];
    __syncthreads();
  }
  float bhr = bhh[col], bhz = bhh[col + H_], bhn = bhh[col + 2 * H_];

#pragma unroll
  for (int i = 0; i < 2; ++i) {
#pragma unroll
    for (int rg = 0; rg < 4; ++rg) {
      int rl = i * 16 + quad * 4 + rg;
      long row = row0 + rl;
      float xr, xz, xn;
      if (ENC) {
        const float* it = (const float*)As3 + rl * 8;
        xr = bcv[0]; xz = bcv[1]; xn = bcv[2];
#pragma unroll
        for (int j = 0; j < 8; ++j) {
          float iv = it[j];
          xr += iv * wc[0][j];
          xz += iv * wc[1][j];
          xn += iv * wc[2][j];
        }
      } else {
        long gx = row * H3_ + col;
        xr = bf2f(xg[gx]); xz = bf2f(xg[gx + H_]); xn = bf2f(xg[gx + 2 * H_]);
      }
      float r = sig_fast(xr + acc[0][i][rg] + bhr);
      float z = sig_fast(xz + acc[1][i][rg] + bhz);
      float n = tanh_fast(xn + r * (acc[2][i][rg] + bhn));
      long hi = row * H_ + col;
      float hp = bf2f(Aprev[hi]);                 // bf16 h_{t-1} (L2-hot)
      float hv = (1.f - z) * n + z * hp;
      hout[hi] = f2bf(hv);
    }
  }
}

// ---- batched out_seq: one block per b. ew3/a4 arrive pre-scaled by LOG2E2,
// staged as f32 in LDS with conflict-free contiguous-quarter access.
// tanh(x) = 1 - 2*rcp(exp2(x*LOG2E2)+1); "1" folded into svtot=sum(v2).
__global__ __launch_bounds__(256) void out_seq_all(
    const short* __restrict__ ew3,   // (Lenc, B, W) bf16, prescaled
    const short* __restrict__ a4,    // (Ldec, B, W) bf16, prescaled
    const float* __restrict__ v2,
    float* __restrict__ out)
{
  __shared__ float se[L_ * W_];   // 20 KB
  __shared__ float sa[L_ * W_];   // 20 KB
  const int b = blockIdx.x;
  const int tid = threadIdx.x;
  for (int i = tid; i < L_ * 128; i += 256) {
    int row = i >> 7, q = i & 127;
    s4v ev = *(const s4v*)(ew3 + ((long)row * B_ + b) * W_ + q * 4);
    s4v av = *(const s4v*)(a4 + ((long)row * B_ + b) * W_ + q * 4);
    f4v e, a;
#pragma unroll
    for (int j = 0; j < 4; ++j) { e[j] = bf2f(ev[j]); a[j] = bf2f(av[j]); }
    *(f4v*)(se + row * W_ + q * 4) = e;
    *(f4v*)(sa + row * W_ + q * 4) = a;
  }
  const int wave = tid >> 6, lane = tid & 63;
  float sv0[4], sv1[4], svtot = 0.f;
#pragma unroll
  for (int q = 0; q < 4; ++q) {
    float v = v2[lane * 4 + q];
    sv0[q] = -2.f * v; svtot += v;
    v = v2[256 + lane * 4 + q];
    sv1[q] = -2.f * v; svtot += v;
  }
#pragma unroll
  for (int off = 32; off; off >>= 1) svtot += __shfl_down(svtot, off, 64);
  svtot = __shfl(svtot, 0, 64);
  __syncthreads();

  int tprev = -1;
  f4v a0, a1;
#pragma unroll
  for (int pp = 0; pp < 25; ++pp) {
    int p = wave * 25 + pp;       // 100 (t,l) pairs over 4 waves
    int t = p / L_, l = p - t * L_;
    if (t != tprev) {             // wave-uniform branch; a-regs reused
      a0 = *(const f4v*)(sa + t * W_ + lane * 4);
      a1 = *(const f4v*)(sa + t * W_ + 256 + lane * 4);
      tprev = t;
    }
    f4v e0 = *(const f4v*)(se + l * W_ + lane * 4);
    f4v e1 = *(const f4v*)(se + l * W_ + 256 + lane * 4);
    float acc = 0.f;
#pragma unroll
    for (int q = 0; q < 4; ++q) {
      float x0 = __builtin_amdgcn_exp2f(e0[q] + a0[q]);
      acc += sv0[q] * __builtin_amdgcn_rcpf(x0 + 1.f);
      float x1 = __builtin_amdgcn_exp2f(e1[q] + a1[q]);
      acc += sv1[q] * __builtin_amdgcn_rcpf(x1 + 1.f);
    }
#pragma unroll
    for (int off = 32; off; off >>= 1) acc += __shfl_down(acc, off, 64);
    if (lane == 0) out[((long)b * L_ + t) * L_ + l] = svtot + acc;
  }
}

// ---- batched out_ori: one wave per (b,t). ----
__global__ __launch_bounds__(256) void out_ori_all(
    const short* __restrict__ dh,    // (Ldec, B, H) bf16
    const float* __restrict__ wori, const float* __restrict__ bori,
    float* __restrict__ out)
{
  int wid = (blockIdx.x * 256 + threadIdx.x) >> 6;   // b*L + t
  int lane = threadIdx.x & 63;
  int b = wid / L_, t = wid - b * L_;
  s8v hv = *(const s8v*)(dh + ((long)t * B_ + b) * H_ + lane * 8);
  float hf[8];
#pragma unroll
  for (int j = 0; j < 8; ++j) hf[j] = bf2f(hv[j]);
  float res[6];
#pragma unroll
  for (int o = 0; o < 6; ++o) {
    const float* wr = wori + (long)o * H3_ + H_ + lane * 8;
    float acc = 0.f;
#pragma unroll
    for (int j = 0; j < 8; ++j) acc += hf[j] * wr[j];
#pragma unroll
    for (int off = 32; off; off >>= 1) acc += __shfl_down(acc, off, 64);
    res[o] = acc;
  }
  if (lane == 0) {
    float* po = out + ORI_BASE + ((long)b * L_ + t) * 6;
#pragma unroll
    for (int o = 0; o < 6; ++o) po[o] = res[o] + bori[o];
  }
}

extern "C" void kernel_launch(void* const* d_in, const int* in_sizes, int n_in,
                              void* d_out, int out_size, void* d_ws, size_t ws_size,
                              hipStream_t stream)
{
  const float* items   = (const float*)d_in[0];
  const float* dec_in  = (const float*)d_in[1];
  const float* emb_w   = (const float*)d_in[2];
  const float* emb_b   = (const float*)d_in[3];
  const float* enc_wih = (const float*)d_in[4];
  const float* enc_whh = (const float*)d_in[5];
  const float* enc_bih = (const float*)d_in[6];
  const float* enc_bhh = (const float*)d_in[7];
  const float* dec_wih = (const float*)d_in[8];
  const float* dec_whh = (const float*)d_in[9];
  const float* dec_bih = (const float*)d_in[10];
  const float* dec_bhh = (const float*)d_in[11];
  const float* w3      = (const float*)d_in[14];
  const float* w4      = (const float*)d_in[15];
  const float* v2      = (const float*)d_in[20];
  const float* wori    = (const float*)d_in[23];
  const float* bori    = (const float*)d_in[24];
  float* out = (float*)d_out;

  char* ws = (char*)d_ws;
  size_t off = 0;
  auto alloc = [&](size_t bytes) { size_t o = off; off += (bytes + 255) & ~255UL; return o; };
  float* Wc       = (float*)(ws + alloc(H3_ * IN_ * 4));
  float* bc       = (float*)(ws + alloc(H3_ * 4));
  short* xgb      = (short*)(ws + alloc((size_t)B_ * H3_ * 2));          // 12 MiB
  short* enc_hist = (short*)(ws + alloc((size_t)11 * B_ * H_ * 2));      // 44 MiB
  short* dec_hist = (short*)(ws + alloc((size_t)L_ * B_ * H_ * 2));      // 40 MiB
  short* ew3      = (short*)(ws + alloc((size_t)L_ * B_ * W_ * 2));      // 40 MiB
  short* a4       = (short*)(ws + alloc((size_t)L_ * B_ * W_ * 2));      // 40 MiB
  short* W2e      = (short*)(ws + alloc((size_t)H3_ * H_ * 2));          // 1.5 MiB
  short* W2d      = (short*)(ws + alloc((size_t)H3_ * H_ * 2));          // 1.5 MiB
  short* wih_d    = (short*)(ws + alloc((size_t)H3_ * H_ * 2));
  short* w3b      = (short*)(ws + alloc((size_t)W_ * H_ * 2));
  short* w4b      = (short*)(ws + alloc((size_t)W_ * H_ * 2));
  short* decb     = (short*)(ws + alloc((size_t)B_ * H_ * 2));           // 4 MiB

  // ---- prep ----
  prep_all<<<(425984 + 255) / 256, 256, 0, stream>>>(
      dec_wih, wih_d, w3, w3b, w4, w4b, dec_in, decb);
  prep_w2<<<768, 256, 0, stream>>>(enc_whh, dec_whh, W2e, W2d);
  build_wc<<<384, 256, 0, stream>>>(enc_wih, emb_w, emb_b, enc_bih, Wc, bc);

  hipMemsetAsync(enc_hist, 0, (size_t)B_ * H_ * 2, stream);      // slice 0 = 0

  // xg_dec = dec_in @ dec_wih^T + dec_bih (fixed across decoder steps), bf16
  gemm_bf16<short><<<dim3(12, 32), 256, 0, stream>>>(
      decb, H_, wih_d, H_, dec_bih, xgb, H3_, H_, 1.f);

  // ---- Encoder recurrence: single fused kernel per step (xg inline) ----
  for (int t = 0; t < L_; ++t) {
    gru_fused<true><<<2048, 128, 0, stream>>>(
        enc_hist + (size_t)t * B_ * H_, W2e, enc_bhh, nullptr,
        items + (size_t)t * IN_, Wc, bc,
        enc_hist + (size_t)(t + 1) * B_ * H_);
  }

  // ---- Decoder recurrence ----
  for (int t = 0; t < L_; ++t) {
    const short* prev = (t == 0) ? enc_hist + (size_t)10 * B_ * H_
                                 : dec_hist + (size_t)(t - 1) * B_ * H_;
    gru_fused<false><<<2048, 128, 0, stream>>>(
        prev, W2d, dec_bhh, xgb, nullptr, nullptr, nullptr,
        dec_hist + (size_t)t * B_ * H_);
  }

  // ---- Merged batched epilogue (ew3/a4 prescaled by LOG2E2) ----
  gemm_epi<<<dim3(4, 320, 2), 256, 0, stream>>>(
      enc_hist + (size_t)B_ * H_, dec_hist, w3b, w4b, ew3, a4);
  out_seq_all<<<B_, 256, 0, stream>>>(ew3, a4, v2, out);
  out_ori_all<<<(B_ * L_) / 4, 256, 0, stream>>>(dec_hist, wori, bori, out);
}

// Round 10
// 530.788 us; speedup vs baseline: 1.0862x; 1.0862x over previous
//
#include <hip/hip_runtime.h>
#include <hip/hip_bf16.h>

// PointerNetwork: B=4096, L=10, IN=8, H=512, W=512. fp32 in/out, ws=256MiB.
// log_softmax over size-1 axes => hi==he==0. Surviving compute:
//   enc GRU, ew3 = h_enc @ w3^T, dec GRU, a4 = h_dec @ w4^T,
//   out_seq = tanh(ew3+a4)@v2, out_ori = h_dec @ wori[:,H:2H]^T + bori.
// Round 16 = R8 skeleton (proven 534us: gru 64x64 LDS-staged dbuf + XCD
// row-panel swizzle + bf16 h + merged epi) with out_seq_all REWRITTEN:
// the old version was LDS-pipe-bound (600 ds_bpermute from __shfl reduce +
// 400 f32 reads per block). New: dot via MFMA (s=rcp(exp2+1) bf16 A-frag x
// broadcast-v2 B-frag; out = sum(v2) - 2*acc), bf16 LDS staging with XOR
// chunk swizzle, v2 frags in registers, 448-float LDS partial combine.

#define B_   4096
#define L_   10
#define IN_  8
#define H_   512
#define H3_  1536
#define W_   512
#define ORI_BASE (B_ * L_ * L_)   // 409600

typedef __attribute__((ext_vector_type(8))) short s8v;
typedef __attribute__((ext_vector_type(4))) short s4v;
typedef __attribute__((ext_vector_type(4))) float f4v;

#define LOG2E  1.4426950408889634f
#define LOG2E2 2.8853900817779268f

__device__ __forceinline__ float sig_fast(float x) {
  float e = __builtin_amdgcn_exp2f(-x * LOG2E);
  return __builtin_amdgcn_rcpf(1.f + e);
}
__device__ __forceinline__ float tanh_fast(float x) {
  float e = __builtin_amdgcn_exp2f(x * LOG2E2);
  return 1.f - 2.f * __builtin_amdgcn_rcpf(e + 1.f);
}
__device__ __forceinline__ short f2bf(float f) {
  __hip_bfloat16 h = __float2bfloat16(f);
  return __builtin_bit_cast(short, h);
}
__device__ __forceinline__ float bf2f(short s) {
  __hip_bfloat16 h = __builtin_bit_cast(__hip_bfloat16, s);
  return __bfloat162float(h);
}
__device__ __forceinline__ void stc(float* p, float v) { *p = v; }
__device__ __forceinline__ void stc(short* p, float v) { *p = f2bf(v); }

// ---- fused prep: all fp32->bf16 conversions in one dispatch (6 segments) ----
__global__ __launch_bounds__(256) void prep_all(
    const float* __restrict__ s0, short* __restrict__ d0,   // enc_whh 786432
    const float* __restrict__ s1, short* __restrict__ d1,   // dec_whh 786432
    const float* __restrict__ s2, short* __restrict__ d2,   // dec_wih 786432
    const float* __restrict__ s3, short* __restrict__ d3,   // w3      262144
    const float* __restrict__ s4, short* __restrict__ d4,   // w4      262144
    const float* __restrict__ s5, short* __restrict__ d5)   // dec_in  2097152
{
  long i8 = (long)blockIdx.x * 256 + threadIdx.x;   // unit = 8 elements
  const float* s; short* d; long off;
  if      (i8 < 98304)  { s = s0; d = d0; off = i8; }
  else if (i8 < 196608) { s = s1; d = d1; off = i8 - 98304; }
  else if (i8 < 294912) { s = s2; d = d2; off = i8 - 196608; }
  else if (i8 < 327680) { s = s3; d = d3; off = i8 - 294912; }
  else if (i8 < 360448) { s = s4; d = d4; off = i8 - 327680; }
  else if (i8 < 622592) { s = s5; d = d5; off = i8 - 360448; }
  else return;
  const float* sp = s + off * 8;
  s8v v;
#pragma unroll
  for (int j = 0; j < 8; ++j) v[j] = f2bf(sp[j]);
  *(s8v*)(d + off * 8) = v;
}

// Fold embedding into encoder input weight. One wave per g-row (1536 waves).
__global__ __launch_bounds__(256) void build_wc(
    const float* __restrict__ enc_wih, const float* __restrict__ emb_w,
    const float* __restrict__ emb_b, const float* __restrict__ enc_bih,
    float* __restrict__ Wc, float* __restrict__ bc)
{
  __shared__ float se[H_ * IN_];   // 16 KB
  __shared__ float sb[H_];         // 2 KB
  const int tid = threadIdx.x;
  for (int i = tid; i < H_ * IN_; i += 256) se[i] = emb_w[i];
  for (int i = tid; i < H_; i += 256) sb[i] = emb_b[i];
  __syncthreads();
  int g = (blockIdx.x * 256 + tid) >> 6;
  int lane = tid & 63;
  const float* wr = enc_wih + (long)g * H_ + lane * 8;
  float w8[8];
#pragma unroll
  for (int j = 0; j < 8; ++j) w8[j] = wr[j];
  float acc[9] = {};
#pragma unroll
  for (int kk = 0; kk < 8; ++kk) {
    int k = lane * 8 + kk;
#pragma unroll
    for (int j = 0; j < 8; ++j) acc[j] += w8[kk] * se[k * IN_ + j];
    acc[8] += w8[kk] * sb[k];
  }
#pragma unroll
  for (int j = 0; j < 9; ++j)
#pragma unroll
    for (int off = 32; off; off >>= 1) acc[j] += __shfl_down(acc[j], off, 64);
  if (lane == 0) {
#pragma unroll
    for (int j = 0; j < 8; ++j) Wc[g * IN_ + j] = acc[j];
    bc[g] = acc[8] + enc_bih[g];
  }
}

// ---- Pipelined bf16 MFMA GEMM: C[M,N] = (A@B^T (+bias))*scale.
// 128x128 tile, BK=64, double-buffered LDS (64KB, 2 blk/CU), counted
// vmcnt(8), XOR-swizzled 16B chunks (both-sides), setprio around MFMA.
template <typename CT>
__global__ __launch_bounds__(256) void gemm_bf16(
    const short* __restrict__ A, long lda,
    const short* __restrict__ Bw, long ldb,
    const float* __restrict__ bias,
    CT* __restrict__ C, long ldc, int K, float scale)
{
  __shared__ short As[2][128 * 64];   // 32 KB
  __shared__ short Bs[2][128 * 64];   // 32 KB
  const int tid = threadIdx.x;
  const long row0 = (long)blockIdx.y * 128;
  const long col0 = (long)blockIdx.x * 128;
  const int wave = tid >> 6, lane = tid & 63;
  const int wm = (wave & 1) * 64, wn = (wave >> 1) * 64;
  const int r16 = lane & 15, quad = lane >> 4;
  const int sw = r16 & 7;
  f4v acc[4][4] = {};

  auto stage = [&](int buf, int k0) {
#pragma unroll
    for (int r = 0; r < 4; ++r) {             // A: 128x64 = 1024 chunks
      int idx = r * 256 + tid;
      int m = idx >> 3, c8 = idx & 7;
      int src = c8 ^ (m & 7);
      __builtin_amdgcn_global_load_lds(
          (const __attribute__((address_space(1))) void*)(A + (row0 + m) * lda + k0 + src * 8),
          (__attribute__((address_space(3))) void*)(&As[buf][idx * 8]), 16, 0, 0);
    }
#pragma unroll
    for (int r = 0; r < 4; ++r) {             // B: 128x64 = 1024 chunks
      int idx = r * 256 + tid;
      int m = idx >> 3, c8 = idx & 7;
      int src = c8 ^ (m & 7);
      __builtin_amdgcn_global_load_lds(
          (const __attribute__((address_space(1))) void*)(Bw + (col0 + m) * ldb + k0 + src * 8),
          (__attribute__((address_space(3))) void*)(&Bs[buf][idx * 8]), 16, 0, 0);
    }
  };

  const int nk = K >> 6;
  stage(0, 0);
  for (int k = 0; k < nk; ++k) {
    if (k < nk - 1) {
      stage((k + 1) & 1, (k + 1) * 64);
      asm volatile("s_waitcnt vmcnt(8)" ::: "memory");   // cur's 8 loads done
    } else {
      asm volatile("s_waitcnt vmcnt(0)" ::: "memory");
    }
    __builtin_amdgcn_s_barrier();
    const short* Asc = As[k & 1];
    const short* Bsc = Bs[k & 1];
    s8v af[4][2], bf[4][2];
#pragma unroll
    for (int i = 0; i < 4; ++i)
#pragma unroll
      for (int hh = 0; hh < 2; ++hh)
        af[i][hh] = *(const s8v*)&Asc[(wm + i * 16 + r16) * 64 + ((hh * 4 + quad) ^ sw) * 8];
#pragma unroll
    for (int j = 0; j < 4; ++j)
#pragma unroll
      for (int hh = 0; hh < 2; ++hh)
        bf[j][hh] = *(const s8v*)&Bsc[(wn + j * 16 + r16) * 64 + ((hh * 4 + quad) ^ sw) * 8];
    __builtin_amdgcn_s_setprio(1);
#pragma unroll
    for (int hh = 0; hh < 2; ++hh)
#pragma unroll
      for (int i = 0; i < 4; ++i)
#pragma unroll
        for (int j = 0; j < 4; ++j)
          acc[i][j] = __builtin_amdgcn_mfma_f32_16x16x32_bf16(af[i][hh], bf[j][hh], acc[i][j], 0, 0, 0);
    __builtin_amdgcn_s_setprio(0);
    __builtin_amdgcn_s_barrier();
  }

#pragma unroll
  for (int i = 0; i < 4; ++i) {
    long rbase = row0 + wm + i * 16 + quad * 4;
#pragma unroll
    for (int j = 0; j < 4; ++j) {
      long c = col0 + wn + j * 16 + r16;
      float bv = bias ? bias[c] : 0.f;
#pragma unroll
      for (int rg = 0; rg < 4; ++rg)
        stc(&C[(rbase + rg) * ldc + c], (acc[i][j][rg] + bv) * scale);
    }
  }
}

// ---- Merged epilogue GEMM: z=0 -> ew3 = enc_hist@w3^T; z=1 -> a4 =
// dec_hist@w4^T. Same pipelined body, output *LOG2E2 as bf16.
__global__ __launch_bounds__(256) void gemm_epi(
    const short* __restrict__ Ae, const short* __restrict__ Ad,
    const short* __restrict__ w3b, const short* __restrict__ w4b,
    short* __restrict__ Ce, short* __restrict__ Cd)
{
  const short* A  = blockIdx.z ? Ad : Ae;
  const short* Bw = blockIdx.z ? w4b : w3b;
  short* C        = blockIdx.z ? Cd : Ce;
  __shared__ short As[2][128 * 64];
  __shared__ short Bs[2][128 * 64];
  const int tid = threadIdx.x;
  const long row0 = (long)blockIdx.y * 128;
  const long col0 = (long)blockIdx.x * 128;
  const int wave = tid >> 6, lane = tid & 63;
  const int wm = (wave & 1) * 64, wn = (wave >> 1) * 64;
  const int r16 = lane & 15, quad = lane >> 4;
  const int sw = r16 & 7;
  f4v acc[4][4] = {};

  auto stage = [&](int buf, int k0) {
#pragma unroll
    for (int r = 0; r < 4; ++r) {
      int idx = r * 256 + tid;
      int m = idx >> 3, c8 = idx & 7;
      int src = c8 ^ (m & 7);
      __builtin_amdgcn_global_load_lds(
          (const __attribute__((address_space(1))) void*)(A + (row0 + m) * H_ + k0 + src * 8),
          (__attribute__((address_space(3))) void*)(&As[buf][idx * 8]), 16, 0, 0);
    }
#pragma unroll
    for (int r = 0; r < 4; ++r) {
      int idx = r * 256 + tid;
      int m = idx >> 3, c8 = idx & 7;
      int src = c8 ^ (m & 7);
      __builtin_amdgcn_global_load_lds(
          (const __attribute__((address_space(1))) void*)(Bw + (col0 + m) * H_ + k0 + src * 8),
          (__attribute__((address_space(3))) void*)(&Bs[buf][idx * 8]), 16, 0, 0);
    }
  };

  stage(0, 0);
  for (int k = 0; k < 8; ++k) {
    if (k < 7) {
      stage((k + 1) & 1, (k + 1) * 64);
      asm volatile("s_waitcnt vmcnt(8)" ::: "memory");
    } else {
      asm volatile("s_waitcnt vmcnt(0)" ::: "memory");
    }
    __builtin_amdgcn_s_barrier();
    const short* Asc = As[k & 1];
    const short* Bsc = Bs[k & 1];
    s8v af[4][2], bf[4][2];
#pragma unroll
    for (int i = 0; i < 4; ++i)
#pragma unroll
      for (int hh = 0; hh < 2; ++hh)
        af[i][hh] = *(const s8v*)&Asc[(wm + i * 16 + r16) * 64 + ((hh * 4 + quad) ^ sw) * 8];
#pragma unroll
    for (int j = 0; j < 4; ++j)
#pragma unroll
      for (int hh = 0; hh < 2; ++hh)
        bf[j][hh] = *(const s8v*)&Bsc[(wn + j * 16 + r16) * 64 + ((hh * 4 + quad) ^ sw) * 8];
    __builtin_amdgcn_s_setprio(1);
#pragma unroll
    for (int hh = 0; hh < 2; ++hh)
#pragma unroll
      for (int i = 0; i < 4; ++i)
#pragma unroll
        for (int j = 0; j < 4; ++j)
          acc[i][j] = __builtin_amdgcn_mfma_f32_16x16x32_bf16(af[i][hh], bf[j][hh], acc[i][j], 0, 0, 0);
    __builtin_amdgcn_s_setprio(0);
    __builtin_amdgcn_s_barrier();
  }

#pragma unroll
  for (int i = 0; i < 4; ++i) {
    long rbase = row0 + wm + i * 16 + quad * 4;
#pragma unroll
    for (int j = 0; j < 4; ++j) {
      long c = col0 + wn + j * 16 + r16;
#pragma unroll
      for (int rg = 0; rg < 4; ++rg)
        C[(rbase + rg) * W_ + c] = f2bf(acc[i][j][rg] * LOG2E2);
    }
  }
}

// ---- Fused GRU step (R8 proven). Tile: 64 rows x 64 cols x 3 gates.
// Flat grid 512, 256 thr (4 waves, 2 blk/CU). by=flat&63, bx=flat>>6 ->
// row-panel sharers same-XCD. BK=64, dbuf LDS (64KB), counted vmcnt(8),
// XOR-swizzle, setprio, bf16-h blend (no fp32 master).
template <bool ENC>
__global__ __launch_bounds__(256) void gru_fused(
    const short* __restrict__ Aprev,  // (B,H) bf16 h_{t-1}
    const short* __restrict__ Whh,    // (3H,H) bf16
    const float* __restrict__ bhh,    // (3H)
    const short* __restrict__ xg,     // (B,3H) bf16 (decoder)
    const float* __restrict__ items_t,// encoder: &items[0][t][0], row stride 80
    const float* __restrict__ Wc,     // (3H,8)
    const float* __restrict__ bc,     // (3H)
    short* __restrict__ hout)         // (B,H) bf16 history slice
{
  __shared__ short As[2][64 * 64];    // 16 KB
  __shared__ short Bs[2][192 * 64];   // 48 KB
  const int tid = threadIdx.x;
  const int flat = blockIdx.x;
  const int by = flat & 63, bx = flat >> 6;   // XCD row-panel swizzle
  const long row0 = (long)by * 64;
  const int col0 = bx * 64;
  const int wave = tid >> 6, lane = tid & 63;
  const int r16 = lane & 15, quad = lane >> 4;
  const int sw = r16 & 7;

  f4v acc[3][4] = {};   // [gate][frag-row]

  auto stage = [&](int buf, int k0) {
#pragma unroll
    for (int r = 0; r < 2; ++r) {             // A: 64x64 = 512 chunks
      int idx = r * 256 + tid;
      int m = idx >> 3, c8 = idx & 7;
      int src = c8 ^ (m & 7);
      __builtin_amdgcn_global_load_lds(
          (const __attribute__((address_space(1))) void*)(Aprev + (row0 + m) * H_ + k0 + src * 8),
          (__attribute__((address_space(3))) void*)(&As[buf][idx * 8]), 16, 0, 0);
    }
#pragma unroll
    for (int r = 0; r < 6; ++r) {             // B: 192x64 = 1536 chunks
      int idx = r * 256 + tid;
      int m = idx >> 3, c8 = idx & 7;
      int src = c8 ^ (m & 7);
      int g = m >> 6, cc = m & 63;
      __builtin_amdgcn_global_load_lds(
          (const __attribute__((address_space(1))) void*)(Whh + ((long)g * H_ + col0 + cc) * H_ + k0 + src * 8),
          (__attribute__((address_space(3))) void*)(&Bs[buf][idx * 8]), 16, 0, 0);
    }
  };

  stage(0, 0);
  int cur = 0;
  for (int k = 0; k < 8; ++k) {
    if (k < 7) {
      stage(cur ^ 1, (k + 1) * 64);
      asm volatile("s_waitcnt vmcnt(8)" ::: "memory");   // cur's 8 loads done
    } else {
      asm volatile("s_waitcnt vmcnt(0)" ::: "memory");
    }
    __builtin_amdgcn_s_barrier();
    s8v af[4][2], bf[3][2];
#pragma unroll
    for (int i = 0; i < 4; ++i)
#pragma unroll
      for (int hh = 0; hh < 2; ++hh)
        af[i][hh] = *(const s8v*)&As[cur][(i * 16 + r16) * 64 + ((hh * 4 + quad) ^ sw) * 8];
#pragma unroll
    for (int g = 0; g < 3; ++g)
#pragma unroll
      for (int hh = 0; hh < 2; ++hh)
        bf[g][hh] = *(const s8v*)&Bs[cur][(g * 64 + wave * 16 + r16) * 64 + ((hh * 4 + quad) ^ sw) * 8];
    __builtin_amdgcn_s_setprio(1);
#pragma unroll
    for (int hh = 0; hh < 2; ++hh)
#pragma unroll
      for (int g = 0; g < 3; ++g)
#pragma unroll
        for (int i = 0; i < 4; ++i)
          acc[g][i] = __builtin_amdgcn_mfma_f32_16x16x32_bf16(af[i][hh], bf[g][hh], acc[g][i], 0, 0, 0);
    __builtin_amdgcn_s_setprio(0);
    __builtin_amdgcn_s_barrier();
    cur ^= 1;
  }

  // Column owned by this thread (C/D layout: col=lane&15, row=quad*4+reg).
  const int col = col0 + wave * 16 + r16;
  float wc[3][8], bcv[3];
  if (ENC) {
#pragma unroll
    for (int g = 0; g < 3; ++g) {
      const float* wr = Wc + ((long)g * H_ + col) * IN_;
#pragma unroll
      for (int j = 0; j < 8; ++j) wc[g][j] = wr[j];
      bcv[g] = bc[g * H_ + col];
    }
    // stage items rows into LDS (reuse As): 64 rows x 8 fp32
    float* itemS = (float*)As;
    int i2 = tid * 2;
    int m = i2 >> 3, j = i2 & 7;
    itemS[i2] = items_t[(row0 + m) * (L_ * IN_) + j];
    itemS[i2 + 1] = items_t[(row0 + m) * (L_ * IN_) + j + 1];
    __syncthreads();
  }
  float bhr = bhh[col], bhz = bhh[col + H_], bhn = bhh[col + 2 * H_];

#pragma unroll
  for (int i = 0; i < 4; ++i) {
#pragma unroll
    for (int rg = 0; rg < 4; ++rg) {
      int rl = i * 16 + quad * 4 + rg;
      long row = row0 + rl;
      float xr, xz, xn;
      if (ENC) {
        const float* it = (const float*)As + rl * 8;
        xr = bcv[0]; xz = bcv[1]; xn = bcv[2];
#pragma unroll
        for (int j = 0; j < 8; ++j) {
          float iv = it[j];
          xr += iv * wc[0][j];
          xz += iv * wc[1][j];
          xn += iv * wc[2][j];
        }
      } else {
        long gx = row * H3_ + col;
        xr = bf2f(xg[gx]); xz = bf2f(xg[gx + H_]); xn = bf2f(xg[gx + 2 * H_]);
      }
      float r = sig_fast(xr + acc[0][i][rg] + bhr);
      float z = sig_fast(xz + acc[1][i][rg] + bhz);
      float n = tanh_fast(xn + r * (acc[2][i][rg] + bhn));
      long hi = row * H_ + col;
      float hp = bf2f(Aprev[hi]);                 // bf16 h_{t-1} (L2-hot)
      float hv = (1.f - z) * n + z * hp;
      hout[hi] = f2bf(hv);
    }
  }
}

// ---- out_seq via MFMA dot: one block per b, 256 thr (4 waves).
// ew3/a4 (bf16, prescaled by LOG2E2) staged bf16 in LDS with chunk swizzle
// c^=(row&7). Pair p = t*10+l (100 pairs, 7 groups of 16 rows). Wave w owns
// k-chunks kc = w*4..w*4+3. Per unit (g,kc): lane(r16,quad) computes
// s[k]=rcp(exp2(e+a)+1) for pair g*16+r16, k=kc*32+quad*8.. as bf16 A-frag;
// B-frag = v2[k] broadcast to all cols (from registers). out = sum(v2)-2*dot
// (tanh = 1-2s with "1" folded into svtot). Cross-wave combine via 448-f32
// LDS partials. Eliminates the old 600 ds_bpermute/block shuffle reduce.
__global__ __launch_bounds__(256) void out_seq_all(
    const short* __restrict__ ew3,   // (Lenc, B, W) bf16, prescaled
    const short* __restrict__ a4,    // (Ldec, B, W) bf16, prescaled
    const float* __restrict__ v2,
    float* __restrict__ out)
{
  __shared__ short s_e[L_ * W_];        // 10 KB
  __shared__ short s_a[L_ * W_];        // 10 KB
  __shared__ short v2b[W_];             // 1 KB
  __shared__ float part[7 * 4 * 4 * 4]; // [g][quad][w][rg]
  __shared__ float svtot_s;
  const int b = blockIdx.x;
  const int tid = threadIdx.x;
  const int w = tid >> 6, lane = tid & 63;
  const int r16 = lane & 15, quad = lane >> 4;

  // stage ew3/a4 rows (10 x 512 bf16), chunk-swizzled; coalesced global reads
  for (int i = tid; i < L_ * 64; i += 256) {
    int row = i >> 6, c = i & 63;
    int swc = (c ^ (row & 7)) * 8;
    *(s8v*)(s_e + row * W_ + swc) = *(const s8v*)(ew3 + ((long)row * B_ + b) * W_ + c * 8);
    *(s8v*)(s_a + row * W_ + swc) = *(const s8v*)(a4  + ((long)row * B_ + b) * W_ + c * 8);
  }
  {
    int i = tid * 2;
    v2b[i] = f2bf(v2[i]);
    v2b[i + 1] = f2bf(v2[i + 1]);
  }
  if (w == 0) {   // svtot = sum(v2)
    float s = 0.f;
    const float* vp = v2 + lane * 8;
#pragma unroll
    for (int j = 0; j < 8; ++j) s += vp[j];
#pragma unroll
    for (int off = 32; off; off >>= 1) s += __shfl_down(s, off, 64);
    if (lane == 0) svtot_s = s;
  }
  __syncthreads();

  // v2 B-fragments for this wave's 4 k-chunks (broadcast over r16)
  s8v vfrag[4];
#pragma unroll
  for (int j = 0; j < 4; ++j)
    vfrag[j] = *(const s8v*)(v2b + (w * 4 + j) * 32 + quad * 8);

  f4v acc[7] = {};
#pragma unroll
  for (int g = 0; g < 7; ++g) {
    int p = g * 16 + r16;
    int t = (p * 205) >> 11;          // p/10 (valid p<1028)
    int l = p - t * 10;
    if (t > 9) t = 9;                 // dead slots p>=100: clamp, discard later
    const short* ep = s_e + l * W_;
    const short* ap = s_a + t * W_;
    const int le = l & 7, ta = t & 7;
#pragma unroll
    for (int j = 0; j < 4; ++j) {
      int cb = (w * 4 + j) * 4 + quad;
      s8v ev = *(const s8v*)(ep + (cb ^ le) * 8);
      s8v av = *(const s8v*)(ap + (cb ^ ta) * 8);
      s8v sf;
#pragma unroll
      for (int e = 0; e < 8; ++e) {
        float x = bf2f(ev[e]) + bf2f(av[e]);   // already *LOG2E2
        float s = __builtin_amdgcn_rcpf(__builtin_amdgcn_exp2f(x) + 1.f);
        sf[e] = f2bf(s);
      }
      acc[g] = __builtin_amdgcn_mfma_f32_16x16x32_bf16(sf, vfrag[j], acc[g], 0, 0, 0);
    }
  }

  // write per-wave partials (col 0 lanes hold rows quad*4+rg)
  if (r16 == 0) {
#pragma unroll
    for (int g = 0; g < 7; ++g)
      *(f4v*)(part + ((g * 4 + quad) * 4 + w) * 4) = acc[g];
  }
  __syncthreads();
  if (tid < 112) {
    int g = tid >> 4, row = tid & 15;
    int q = row >> 2, rg = row & 3;
    float s = 0.f;
#pragma unroll
    for (int ww = 0; ww < 4; ++ww)
      s += part[((g * 4 + q) * 4 + ww) * 4 + rg];
    int p = g * 16 + row;
    if (p < 100) {
      int t = (p * 205) >> 11;
      int l = p - t * 10;
      out[((long)b * L_ + t) * L_ + l] = svtot_s - 2.f * s;
    }
  }
}

// ---- batched out_ori: one wave per (b,t). ----
__global__ __launch_bounds__(256) void out_ori_all(
    const short* __restrict__ dh,    // (Ldec, B, H) bf16
    const float* __restrict__ wori, const float* __restrict__ bori,
    float* __restrict__ out)
{
  int wid = (blockIdx.x * 256 + threadIdx.x) >> 6;   // b*L + t
  int lane = threadIdx.x & 63;
  int b = wid / L_, t = wid - b * L_;
  s8v hv = *(const s8v*)(dh + ((long)t * B_ + b) * H_ + lane * 8);
  float hf[8];
#pragma unroll
  for (int j = 0; j < 8; ++j) hf[j] = bf2f(hv[j]);
  float res[6];
#pragma unroll
  for (int o = 0; o < 6; ++o) {
    const float* wr = wori + (long)o * H3_ + H_ + lane * 8;
    float acc = 0.f;
#pragma unroll
    for (int j = 0; j < 8; ++j) acc += hf[j] * wr[j];
#pragma unroll
    for (int off = 32; off; off >>= 1) acc += __shfl_down(acc, off, 64);
    res[o] = acc;
  }
  if (lane == 0) {
    float* po = out + ORI_BASE + ((long)b * L_ + t) * 6;
#pragma unroll
    for (int o = 0; o < 6; ++o) po[o] = res[o] + bori[o];
  }
}

extern "C" void kernel_launch(void* const* d_in, const int* in_sizes, int n_in,
                              void* d_out, int out_size, void* d_ws, size_t ws_size,
                              hipStream_t stream)
{
  const float* items   = (const float*)d_in[0];
  const float* dec_in  = (const float*)d_in[1];
  const float* emb_w   = (const float*)d_in[2];
  const float* emb_b   = (const float*)d_in[3];
  const float* enc_wih = (const float*)d_in[4];
  const float* enc_whh = (const float*)d_in[5];
  const float* enc_bih = (const float*)d_in[6];
  const float* enc_bhh = (const float*)d_in[7];
  const float* dec_wih = (const float*)d_in[8];
  const float* dec_whh = (const float*)d_in[9];
  const float* dec_bih = (const float*)d_in[10];
  const float* dec_bhh = (const float*)d_in[11];
  const float* w3      = (const float*)d_in[14];
  const float* w4      = (const float*)d_in[15];
  const float* v2      = (const float*)d_in[20];
  const float* wori    = (const float*)d_in[23];
  const float* bori    = (const float*)d_in[24];
  float* out = (float*)d_out;

  char* ws = (char*)d_ws;
  size_t off = 0;
  auto alloc = [&](size_t bytes) { size_t o = off; off += (bytes + 255) & ~255UL; return o; };
  float* Wc       = (float*)(ws + alloc(H3_ * IN_ * 4));
  float* bc       = (float*)(ws + alloc(H3_ * 4));
  short* xgb      = (short*)(ws + alloc((size_t)B_ * H3_ * 2));          // 12 MiB
  short* enc_hist = (short*)(ws + alloc((size_t)11 * B_ * H_ * 2));      // 44 MiB
  short* dec_hist = (short*)(ws + alloc((size_t)L_ * B_ * H_ * 2));      // 40 MiB
  short* ew3      = (short*)(ws + alloc((size_t)L_ * B_ * W_ * 2));      // 40 MiB
  short* a4       = (short*)(ws + alloc((size_t)L_ * B_ * W_ * 2));      // 40 MiB
  short* whh_e    = (short*)(ws + alloc((size_t)H3_ * H_ * 2));
  short* whh_d    = (short*)(ws + alloc((size_t)H3_ * H_ * 2));
  short* wih_d    = (short*)(ws + alloc((size_t)H3_ * H_ * 2));
  short* w3b      = (short*)(ws + alloc((size_t)W_ * H_ * 2));
  short* w4b      = (short*)(ws + alloc((size_t)W_ * H_ * 2));
  short* decb     = (short*)(ws + alloc((size_t)B_ * H_ * 2));           // 4 MiB

  // ---- prep (one fused conversion dispatch) ----
  prep_all<<<(622592 + 255) / 256, 256, 0, stream>>>(
      enc_whh, whh_e, dec_whh, whh_d, dec_wih, wih_d,
      w3, w3b, w4, w4b, dec_in, decb);
  build_wc<<<384, 256, 0, stream>>>(enc_wih, emb_w, emb_b, enc_bih, Wc, bc);

  hipMemsetAsync(enc_hist, 0, (size_t)B_ * H_ * 2, stream);      // slice 0 = 0

  // xg_dec = dec_in @ dec_wih^T + dec_bih (fixed across decoder steps), bf16
  gemm_bf16<short><<<dim3(12, 32), 256, 0, stream>>>(
      decb, H_, wih_d, H_, dec_bih, xgb, H3_, H_, 1.f);

  // ---- Encoder recurrence: single fused kernel per step (xg inline) ----
  for (int t = 0; t < L_; ++t) {
    gru_fused<true><<<512, 256, 0, stream>>>(
        enc_hist + (size_t)t * B_ * H_, whh_e, enc_bhh, nullptr,
        items + (size_t)t * IN_, Wc, bc,
        enc_hist + (size_t)(t + 1) * B_ * H_);
  }

  // ---- Decoder recurrence ----
  for (int t = 0; t < L_; ++t) {
    const short* prev = (t == 0) ? enc_hist + (size_t)10 * B_ * H_
                                 : dec_hist + (size_t)(t - 1) * B_ * H_;
    gru_fused<false><<<512, 256, 0, stream>>>(
        prev, whh_d, dec_bhh, xgb, nullptr, nullptr, nullptr,
        dec_hist + (size_t)t * B_ * H_);
  }

  // ---- Merged batched epilogue (ew3/a4 prescaled by LOG2E2) ----
  gemm_epi<<<dim3(4, 320, 2), 256, 0, stream>>>(
      enc_hist + (size_t)B_ * H_, dec_hist, w3b, w4b, ew3, a4);
  out_seq_all<<<B_, 256, 0, stream>>>(ew3, a4, v2, out);
  out_ori_all<<<(B_ * L_) / 4, 256, 0, stream>>>(dec_hist, wori, bori, out);
}

// Round 11
// 527.961 us; speedup vs baseline: 1.0920x; 1.0054x over previous
//
#include <hip/hip_runtime.h>
#include <hip/hip_bf16.h>

// PointerNetwork: B=4096, L=10, IN=8, H=512, W=512. fp32 in/out, ws=256MiB.
// log_softmax over size-1 axes => hi==he==0. Surviving compute:
//   enc GRU, ew3 = h_enc @ w3^T, dec GRU, a4 = h_dec @ w4^T,
//   out_seq = tanh(ew3+a4)@v2, out_ori = h_dec @ wori[:,H:2H]^T + bori.
// Round 17 = R10 (530.8us) with gru_fused's B operand moved to REGISTERS:
// keeps R8's proven 64x64 tile / 256 thr / 512 grid / two-barrier / counted
// vmcnt(8) structure; only B comes via W2 pre-rearranged weights (each wave
// fragment = one contiguous 1KB load; fixes R7's stride problem) instead of
// LDS staging (B has zero intra-block sharing; was 3/4 of LDS traffic).
// LDS 64->16KB (A dbuf only), ds_reads/iter 14->8. R9's tile-shrink (the
// actual cause of its regression) NOT repeated.

#define B_   4096
#define L_   10
#define IN_  8
#define H_   512
#define H3_  1536
#define W_   512
#define ORI_BASE (B_ * L_ * L_)   // 409600

typedef __attribute__((ext_vector_type(8))) short s8v;
typedef __attribute__((ext_vector_type(4))) short s4v;
typedef __attribute__((ext_vector_type(4))) float f4v;

#define LOG2E  1.4426950408889634f
#define LOG2E2 2.8853900817779268f

__device__ __forceinline__ float sig_fast(float x) {
  float e = __builtin_amdgcn_exp2f(-x * LOG2E);
  return __builtin_amdgcn_rcpf(1.f + e);
}
__device__ __forceinline__ float tanh_fast(float x) {
  float e = __builtin_amdgcn_exp2f(x * LOG2E2);
  return 1.f - 2.f * __builtin_amdgcn_rcpf(e + 1.f);
}
__device__ __forceinline__ short f2bf(float f) {
  __hip_bfloat16 h = __float2bfloat16(f);
  return __builtin_bit_cast(short, h);
}
__device__ __forceinline__ float bf2f(short s) {
  __hip_bfloat16 h = __builtin_bit_cast(__hip_bfloat16, s);
  return __bfloat162float(h);
}
__device__ __forceinline__ void stc(float* p, float v) { *p = v; }
__device__ __forceinline__ void stc(short* p, float v) { *p = f2bf(v); }

// ---- fused prep: fp32->bf16 conversions in one dispatch (4 segments) ----
__global__ __launch_bounds__(256) void prep_all(
    const float* __restrict__ s2, short* __restrict__ d2,   // dec_wih 786432
    const float* __restrict__ s3, short* __restrict__ d3,   // w3      262144
    const float* __restrict__ s4, short* __restrict__ d4,   // w4      262144
    const float* __restrict__ s5, short* __restrict__ d5)   // dec_in  2097152
{
  long i8 = (long)blockIdx.x * 256 + threadIdx.x;   // unit = 8 elements
  const float* s; short* d; long off;
  if      (i8 < 98304)  { s = s2; d = d2; off = i8; }
  else if (i8 < 131072) { s = s3; d = d3; off = i8 - 98304; }
  else if (i8 < 163840) { s = s4; d = d4; off = i8 - 131072; }
  else if (i8 < 425984) { s = s5; d = d5; off = i8 - 163840; }
  else return;
  const float* sp = s + off * 8;
  s8v v;
#pragma unroll
  for (int j = 0; j < 8; ++j) v[j] = f2bf(sp[j]);
  *(s8v*)(d + off * 8) = v;
}

// ---- W2 weight rearrange for register-B gru (proven correct in R9):
// W2[g][c16][kb][hh][lane][8] bf16; lane=(r16,q): element =
// whh[g*512 + c16*16 + r16][kb*64 + hh*32 + q*8 + e]. One 16B chunk/thread.
__global__ __launch_bounds__(256) void prep_w2(
    const float* __restrict__ enc_whh, const float* __restrict__ dec_whh,
    short* __restrict__ W2e, short* __restrict__ W2d)
{
  int tg = blockIdx.x * 256 + threadIdx.x;  // 0..196607
  const float* src = enc_whh; short* dst = W2e;
  int t = tg;
  if (t >= 98304) { t -= 98304; src = dec_whh; dst = W2d; }
  int l = t & 63;
  int u = t >> 6;
  int hh = u & 1, kb = (u >> 1) & 7, c16 = (u >> 4) & 31, g = u >> 9;
  int row = g * 512 + c16 * 16 + (l & 15);
  int colb = kb * 64 + hh * 32 + (l >> 4) * 8;
  const float* sp = src + (long)row * 512 + colb;
  s8v v;
#pragma unroll
  for (int j = 0; j < 8; ++j) v[j] = f2bf(sp[j]);
  *(s8v*)(dst + (long)t * 8) = v;
}

// Fold embedding into encoder input weight. One wave per g-row (1536 waves).
__global__ __launch_bounds__(256) void build_wc(
    const float* __restrict__ enc_wih, const float* __restrict__ emb_w,
    const float* __restrict__ emb_b, const float* __restrict__ enc_bih,
    float* __restrict__ Wc, float* __restrict__ bc)
{
  __shared__ float se[H_ * IN_];   // 16 KB
  __shared__ float sb[H_];         // 2 KB
  const int tid = threadIdx.x;
  for (int i = tid; i < H_ * IN_; i += 256) se[i] = emb_w[i];
  for (int i = tid; i < H_; i += 256) sb[i] = emb_b[i];
  __syncthreads();
  int g = (blockIdx.x * 256 + tid) >> 6;
  int lane = tid & 63;
  const float* wr = enc_wih + (long)g * H_ + lane * 8;
  float w8[8];
#pragma unroll
  for (int j = 0; j < 8; ++j) w8[j] = wr[j];
  float acc[9] = {};
#pragma unroll
  for (int kk = 0; kk < 8; ++kk) {
    int k = lane * 8 + kk;
#pragma unroll
    for (int j = 0; j < 8; ++j) acc[j] += w8[kk] * se[k * IN_ + j];
    acc[8] += w8[kk] * sb[k];
  }
#pragma unroll
  for (int j = 0; j < 9; ++j)
#pragma unroll
    for (int off = 32; off; off >>= 1) acc[j] += __shfl_down(acc[j], off, 64);
  if (lane == 0) {
#pragma unroll
    for (int j = 0; j < 8; ++j) Wc[g * IN_ + j] = acc[j];
    bc[g] = acc[8] + enc_bih[g];
  }
}

// ---- Pipelined bf16 MFMA GEMM: C[M,N] = (A@B^T (+bias))*scale.
// 128x128 tile, BK=64, double-buffered LDS (64KB, 2 blk/CU), counted
// vmcnt(8), XOR-swizzled 16B chunks (both-sides), setprio around MFMA.
template <typename CT>
__global__ __launch_bounds__(256) void gemm_bf16(
    const short* __restrict__ A, long lda,
    const short* __restrict__ Bw, long ldb,
    const float* __restrict__ bias,
    CT* __restrict__ C, long ldc, int K, float scale)
{
  __shared__ short As[2][128 * 64];   // 32 KB
  __shared__ short Bs[2][128 * 64];   // 32 KB
  const int tid = threadIdx.x;
  const long row0 = (long)blockIdx.y * 128;
  const long col0 = (long)blockIdx.x * 128;
  const int wave = tid >> 6, lane = tid & 63;
  const int wm = (wave & 1) * 64, wn = (wave >> 1) * 64;
  const int r16 = lane & 15, quad = lane >> 4;
  const int sw = r16 & 7;
  f4v acc[4][4] = {};

  auto stage = [&](int buf, int k0) {
#pragma unroll
    for (int r = 0; r < 4; ++r) {             // A: 128x64 = 1024 chunks
      int idx = r * 256 + tid;
      int m = idx >> 3, c8 = idx & 7;
      int src = c8 ^ (m & 7);
      __builtin_amdgcn_global_load_lds(
          (const __attribute__((address_space(1))) void*)(A + (row0 + m) * lda + k0 + src * 8),
          (__attribute__((address_space(3))) void*)(&As[buf][idx * 8]), 16, 0, 0);
    }
#pragma unroll
    for (int r = 0; r < 4; ++r) {             // B: 128x64 = 1024 chunks
      int idx = r * 256 + tid;
      int m = idx >> 3, c8 = idx & 7;
      int src = c8 ^ (m & 7);
      __builtin_amdgcn_global_load_lds(
          (const __attribute__((address_space(1))) void*)(Bw + (col0 + m) * ldb + k0 + src * 8),
          (__attribute__((address_space(3))) void*)(&Bs[buf][idx * 8]), 16, 0, 0);
    }
  };

  const int nk = K >> 6;
  stage(0, 0);
  for (int k = 0; k < nk; ++k) {
    if (k < nk - 1) {
      stage((k + 1) & 1, (k + 1) * 64);
      asm volatile("s_waitcnt vmcnt(8)" ::: "memory");   // cur's 8 loads done
    } else {
      asm volatile("s_waitcnt vmcnt(0)" ::: "memory");
    }
    __builtin_amdgcn_s_barrier();
    const short* Asc = As[k & 1];
    const short* Bsc = Bs[k & 1];
    s8v af[4][2], bf[4][2];
#pragma unroll
    for (int i = 0; i < 4; ++i)
#pragma unroll
      for (int hh = 0; hh < 2; ++hh)
        af[i][hh] = *(const s8v*)&Asc[(wm + i * 16 + r16) * 64 + ((hh * 4 + quad) ^ sw) * 8];
#pragma unroll
    for (int j = 0; j < 4; ++j)
#pragma unroll
      for (int hh = 0; hh < 2; ++hh)
        bf[j][hh] = *(const s8v*)&Bsc[(wn + j * 16 + r16) * 64 + ((hh * 4 + quad) ^ sw) * 8];
    __builtin_amdgcn_s_setprio(1);
#pragma unroll
    for (int hh = 0; hh < 2; ++hh)
#pragma unroll
      for (int i = 0; i < 4; ++i)
#pragma unroll
        for (int j = 0; j < 4; ++j)
          acc[i][j] = __builtin_amdgcn_mfma_f32_16x16x32_bf16(af[i][hh], bf[j][hh], acc[i][j], 0, 0, 0);
    __builtin_amdgcn_s_setprio(0);
    __builtin_amdgcn_s_barrier();
  }

#pragma unroll
  for (int i = 0; i < 4; ++i) {
    long rbase = row0 + wm + i * 16 + quad * 4;
#pragma unroll
    for (int j = 0; j < 4; ++j) {
      long c = col0 + wn + j * 16 + r16;
      float bv = bias ? bias[c] : 0.f;
#pragma unroll
      for (int rg = 0; rg < 4; ++rg)
        stc(&C[(rbase + rg) * ldc + c], (acc[i][j][rg] + bv) * scale);
    }
  }
}

// ---- Merged epilogue GEMM: z=0 -> ew3 = enc_hist@w3^T; z=1 -> a4 =
// dec_hist@w4^T. Same pipelined body, output *LOG2E2 as bf16.
__global__ __launch_bounds__(256) void gemm_epi(
    const short* __restrict__ Ae, const short* __restrict__ Ad,
    const short* __restrict__ w3b, const short* __restrict__ w4b,
    short* __restrict__ Ce, short* __restrict__ Cd)
{
  const short* A  = blockIdx.z ? Ad : Ae;
  const short* Bw = blockIdx.z ? w4b : w3b;
  short* C        = blockIdx.z ? Cd : Ce;
  __shared__ short As[2][128 * 64];
  __shared__ short Bs[2][128 * 64];
  const int tid = threadIdx.x;
  const long row0 = (long)blockIdx.y * 128;
  const long col0 = (long)blockIdx.x * 128;
  const int wave = tid >> 6, lane = tid & 63;
  const int wm = (wave & 1) * 64, wn = (wave >> 1) * 64;
  const int r16 = lane & 15, quad = lane >> 4;
  const int sw = r16 & 7;
  f4v acc[4][4] = {};

  auto stage = [&](int buf, int k0) {
#pragma unroll
    for (int r = 0; r < 4; ++r) {
      int idx = r * 256 + tid;
      int m = idx >> 3, c8 = idx & 7;
      int src = c8 ^ (m & 7);
      __builtin_amdgcn_global_load_lds(
          (const __attribute__((address_space(1))) void*)(A + (row0 + m) * H_ + k0 + src * 8),
          (__attribute__((address_space(3))) void*)(&As[buf][idx * 8]), 16, 0, 0);
    }
#pragma unroll
    for (int r = 0; r < 4; ++r) {
      int idx = r * 256 + tid;
      int m = idx >> 3, c8 = idx & 7;
      int src = c8 ^ (m & 7);
      __builtin_amdgcn_global_load_lds(
          (const __attribute__((address_space(1))) void*)(Bw + (col0 + m) * H_ + k0 + src * 8),
          (__attribute__((address_space(3))) void*)(&Bs[buf][idx * 8]), 16, 0, 0);
    }
  };

  stage(0, 0);
  for (int k = 0; k < 8; ++k) {
    if (k < 7) {
      stage((k + 1) & 1, (k + 1) * 64);
      asm volatile("s_waitcnt vmcnt(8)" ::: "memory");
    } else {
      asm volatile("s_waitcnt vmcnt(0)" ::: "memory");
    }
    __builtin_amdgcn_s_barrier();
    const short* Asc = As[k & 1];
    const short* Bsc = Bs[k & 1];
    s8v af[4][2], bf[4][2];
#pragma unroll
    for (int i = 0; i < 4; ++i)
#pragma unroll
      for (int hh = 0; hh < 2; ++hh)
        af[i][hh] = *(const s8v*)&Asc[(wm + i * 16 + r16) * 64 + ((hh * 4 + quad) ^ sw) * 8];
#pragma unroll
    for (int j = 0; j < 4; ++j)
#pragma unroll
      for (int hh = 0; hh < 2; ++hh)
        bf[j][hh] = *(const s8v*)&Bsc[(wn + j * 16 + r16) * 64 + ((hh * 4 + quad) ^ sw) * 8];
    __builtin_amdgcn_s_setprio(1);
#pragma unroll
    for (int hh = 0; hh < 2; ++hh)
#pragma unroll
      for (int i = 0; i < 4; ++i)
#pragma unroll
        for (int j = 0; j < 4; ++j)
          acc[i][j] = __builtin_amdgcn_mfma_f32_16x16x32_bf16(af[i][hh], bf[j][hh], acc[i][j], 0, 0, 0);
    __builtin_amdgcn_s_setprio(0);
    __builtin_amdgcn_s_barrier();
  }

#pragma unroll
  for (int i = 0; i < 4; ++i) {
    long rbase = row0 + wm + i * 16 + quad * 4;
#pragma unroll
    for (int j = 0; j < 4; ++j) {
      long c = col0 + wn + j * 16 + r16;
#pragma unroll
      for (int rg = 0; rg < 4; ++rg)
        C[(rbase + rg) * W_ + c] = f2bf(acc[i][j][rg] * LOG2E2);
    }
  }
}

// ---- Fused GRU step, Round-17: R8 structure, B in registers.
// Tile: 64 rows x 64 cols x 3 gates. Flat grid 512, 256 thr (4 waves,
// wave owns cols [col0+wave*16,+16) -> c16 = bx*4+wave). by=flat&63,
// bx=flat>>6 (row-panel sharers same-XCD). A in LDS dbuf 16KB (shared),
// XOR-swizzled; B register dbuf from W2 (1KB coalesced wave loads).
// Per iter: issue A(k+1)x2 + B(k+1)x6, vmcnt(8) retires A(k)+B(k);
// two barriers (publish A(k); guard write-after-read on As).
template <bool ENC>
__global__ __launch_bounds__(256) void gru_fused(
    const short* __restrict__ Aprev,  // (B,H) bf16 h_{t-1}
    const short* __restrict__ W2,     // rearranged weights (prep_w2)
    const float* __restrict__ bhh,    // (3H)
    const short* __restrict__ xg,     // (B,3H) bf16 (decoder)
    const float* __restrict__ items_t,// encoder: &items[0][t][0], row stride 80
    const float* __restrict__ Wc,     // (3H,8)
    const float* __restrict__ bc,     // (3H)
    short* __restrict__ hout)         // (B,H) bf16 history slice
{
  __shared__ short As[2][64 * 64];    // 16 KB
  const int tid = threadIdx.x;
  const int flat = blockIdx.x;
  const int by = flat & 63, bx = flat >> 6;   // XCD row-panel swizzle
  const long row0 = (long)by * 64;
  const int col0 = bx * 64;
  const int wave = tid >> 6, lane = tid & 63;
  const int r16 = lane & 15, quad = lane >> 4;
  const int sw = r16 & 7;
  const int c16 = bx * 4 + wave;
  const int col = col0 + wave * 16 + r16;

  f4v acc[3][4] = {};   // [gate][frag-row]
  s8v bfr[2][3][2];     // register B double-buffer (48 VGPR)

  auto stageA = [&](int buf, int k0) {
#pragma unroll
    for (int r = 0; r < 2; ++r) {             // A: 64x64 = 512 chunks
      int idx = r * 256 + tid;
      int m = idx >> 3, c8 = idx & 7;
      int src = c8 ^ (m & 7);
      __builtin_amdgcn_global_load_lds(
          (const __attribute__((address_space(1))) void*)(Aprev + (row0 + m) * H_ + k0 + src * 8),
          (__attribute__((address_space(3))) void*)(&As[buf][idx * 8]), 16, 0, 0);
    }
  };
  auto loadB = [&](s8v (&dst)[3][2], int kb) {
#pragma unroll
    for (int g = 0; g < 3; ++g)
#pragma unroll
      for (int hh = 0; hh < 2; ++hh)
        dst[g][hh] = *(const s8v*)(W2 + ((((long)(g * 32 + c16) * 8 + kb) * 2 + hh) * 512) + lane * 8);
  };

  stageA(0, 0);          // 2 outstanding
  loadB(bfr[0], 0);      // 8 outstanding
  int cur = 0;
  for (int k = 0; k < 8; ++k) {
    if (k < 7) {
      stageA(cur ^ 1, (k + 1) * 64);      // +2
      loadB(bfr[(k + 1) & 1], k + 1);     // +6 -> 16 outstanding
      asm volatile("s_waitcnt vmcnt(8)" ::: "memory");   // retire A(k),B(k)
    } else {
      asm volatile("s_waitcnt vmcnt(0)" ::: "memory");
    }
    __builtin_amdgcn_s_barrier();          // A(k) visible to all waves
    s8v af[4][2];
#pragma unroll
    for (int i = 0; i < 4; ++i)
#pragma unroll
      for (int hh = 0; hh < 2; ++hh)
        af[i][hh] = *(const s8v*)&As[cur][(i * 16 + r16) * 64 + ((hh * 4 + quad) ^ sw) * 8];
    __builtin_amdgcn_s_setprio(1);
#pragma unroll
    for (int hh = 0; hh < 2; ++hh)
#pragma unroll
      for (int g = 0; g < 3; ++g)
#pragma unroll
        for (int i = 0; i < 4; ++i)
          acc[g][i] = __builtin_amdgcn_mfma_f32_16x16x32_bf16(af[i][hh], bfr[k & 1][g][hh], acc[g][i], 0, 0, 0);
    __builtin_amdgcn_s_setprio(0);
    __builtin_amdgcn_s_barrier();          // guard As[cur^1] overwrite next iter
    cur ^= 1;
  }

  // Column owned by this thread (C/D layout: col=lane&15, row=quad*4+reg).
  float wc[3][8], bcv[3];
  if (ENC) {
#pragma unroll
    for (int g = 0; g < 3; ++g) {
      const float* wr = Wc + ((long)g * H_ + col) * IN_;
#pragma unroll
      for (int j = 0; j < 8; ++j) wc[g][j] = wr[j];
      bcv[g] = bc[g * H_ + col];
    }
    // stage items rows into LDS (reuse As): 64 rows x 8 fp32
    float* itemS = (float*)As;
    int i2 = tid * 2;
    int m = i2 >> 3, j = i2 & 7;
    itemS[i2] = items_t[(row0 + m) * (L_ * IN_) + j];
    itemS[i2 + 1] = items_t[(row0 + m) * (L_ * IN_) + j + 1];
    __syncthreads();
  }
  float bhr = bhh[col], bhz = bhh[col + H_], bhn = bhh[col + 2 * H_];

#pragma unroll
  for (int i = 0; i < 4; ++i) {
#pragma unroll
    for (int rg = 0; rg < 4; ++rg) {
      int rl = i * 16 + quad * 4 + rg;
      long row = row0 + rl;
      float xr, xz, xn;
      if (ENC) {
        const float* it = (const float*)As + rl * 8;
        xr = bcv[0]; xz = bcv[1]; xn = bcv[2];
#pragma unroll
        for (int j = 0; j < 8; ++j) {
          float iv = it[j];
          xr += iv * wc[0][j];
          xz += iv * wc[1][j];
          xn += iv * wc[2][j];
        }
      } else {
        long gx = row * H3_ + col;
        xr = bf2f(xg[gx]); xz = bf2f(xg[gx + H_]); xn = bf2f(xg[gx + 2 * H_]);
      }
      float r = sig_fast(xr + acc[0][i][rg] + bhr);
      float z = sig_fast(xz + acc[1][i][rg] + bhz);
      float n = tanh_fast(xn + r * (acc[2][i][rg] + bhn));
      long hi = row * H_ + col;
      float hp = bf2f(Aprev[hi]);                 // bf16 h_{t-1} (L2-hot)
      float hv = (1.f - z) * n + z * hp;
      hout[hi] = f2bf(hv);
    }
  }
}

// ---- out_seq via MFMA dot (R10 proven): one block per b, 256 thr.
__global__ __launch_bounds__(256) void out_seq_all(
    const short* __restrict__ ew3,   // (Lenc, B, W) bf16, prescaled
    const short* __restrict__ a4,    // (Ldec, B, W) bf16, prescaled
    const float* __restrict__ v2,
    float* __restrict__ out)
{
  __shared__ short s_e[L_ * W_];        // 10 KB
  __shared__ short s_a[L_ * W_];        // 10 KB
  __shared__ short v2b[W_];             // 1 KB
  __shared__ float part[7 * 4 * 4 * 4]; // [g][quad][w][rg]
  __shared__ float svtot_s;
  const int b = blockIdx.x;
  const int tid = threadIdx.x;
  const int w = tid >> 6, lane = tid & 63;
  const int r16 = lane & 15, quad = lane >> 4;

  for (int i = tid; i < L_ * 64; i += 256) {
    int row = i >> 6, c = i & 63;
    int swc = (c ^ (row & 7)) * 8;
    *(s8v*)(s_e + row * W_ + swc) = *(const s8v*)(ew3 + ((long)row * B_ + b) * W_ + c * 8);
    *(s8v*)(s_a + row * W_ + swc) = *(const s8v*)(a4  + ((long)row * B_ + b) * W_ + c * 8);
  }
  {
    int i = tid * 2;
    v2b[i] = f2bf(v2[i]);
    v2b[i + 1] = f2bf(v2[i + 1]);
  }
  if (w == 0) {   // svtot = sum(v2)
    float s = 0.f;
    const float* vp = v2 + lane * 8;
#pragma unroll
    for (int j = 0; j < 8; ++j) s += vp[j];
#pragma unroll
    for (int off = 32; off; off >>= 1) s += __shfl_down(s, off, 64);
    if (lane == 0) svtot_s = s;
  }
  __syncthreads();

  s8v vfrag[4];
#pragma unroll
  for (int j = 0; j < 4; ++j)
    vfrag[j] = *(const s8v*)(v2b + (w * 4 + j) * 32 + quad * 8);

  f4v acc[7] = {};
#pragma unroll
  for (int g = 0; g < 7; ++g) {
    int p = g * 16 + r16;
    int t = (p * 205) >> 11;          // p/10 (valid p<1028)
    int l = p - t * 10;
    if (t > 9) t = 9;                 // dead slots p>=100: clamp, discard later
    const short* ep = s_e + l * W_;
    const short* ap = s_a + t * W_;
    const int le = l & 7, ta = t & 7;
#pragma unroll
    for (int j = 0; j < 4; ++j) {
      int cb = (w * 4 + j) * 4 + quad;
      s8v ev = *(const s8v*)(ep + (cb ^ le) * 8);
      s8v av = *(const s8v*)(ap + (cb ^ ta) * 8);
      s8v sf;
#pragma unroll
      for (int e = 0; e < 8; ++e) {
        float x = bf2f(ev[e]) + bf2f(av[e]);   // already *LOG2E2
        float s = __builtin_amdgcn_rcpf(__builtin_amdgcn_exp2f(x) + 1.f);
        sf[e] = f2bf(s);
      }
      acc[g] = __builtin_amdgcn_mfma_f32_16x16x32_bf16(sf, vfrag[j], acc[g], 0, 0, 0);
    }
  }

  if (r16 == 0) {
#pragma unroll
    for (int g = 0; g < 7; ++g)
      *(f4v*)(part + ((g * 4 + quad) * 4 + w) * 4) = acc[g];
  }
  __syncthreads();
  if (tid < 112) {
    int g = tid >> 4, row = tid & 15;
    int q = row >> 2, rg = row & 3;
    float s = 0.f;
#pragma unroll
    for (int ww = 0; ww < 4; ++ww)
      s += part[((g * 4 + q) * 4 + ww) * 4 + rg];
    int p = g * 16 + row;
    if (p < 100) {
      int t = (p * 205) >> 11;
      int l = p - t * 10;
      out[((long)b * L_ + t) * L_ + l] = svtot_s - 2.f * s;
    }
  }
}

// ---- batched out_ori: one wave per (b,t). ----
__global__ __launch_bounds__(256) void out_ori_all(
    const short* __restrict__ dh,    // (Ldec, B, H) bf16
    const float* __restrict__ wori, const float* __restrict__ bori,
    float* __restrict__ out)
{
  int wid = (blockIdx.x * 256 + threadIdx.x) >> 6;   // b*L + t
  int lane = threadIdx.x & 63;
  int b = wid / L_, t = wid - b * L_;
  s8v hv = *(const s8v*)(dh + ((long)t * B_ + b) * H_ + lane * 8);
  float hf[8];
#pragma unroll
  for (int j = 0; j < 8; ++j) hf[j] = bf2f(hv[j]);
  float res[6];
#pragma unroll
  for (int o = 0; o < 6; ++o) {
    const float* wr = wori + (long)o * H3_ + H_ + lane * 8;
    float acc = 0.f;
#pragma unroll
    for (int j = 0; j < 8; ++j) acc += hf[j] * wr[j];
#pragma unroll
    for (int off = 32; off; off >>= 1) acc += __shfl_down(acc, off, 64);
    res[o] = acc;
  }
  if (lane == 0) {
    float* po = out + ORI_BASE + ((long)b * L_ + t) * 6;
#pragma unroll
    for (int o = 0; o < 6; ++o) po[o] = res[o] + bori[o];
  }
}

extern "C" void kernel_launch(void* const* d_in, const int* in_sizes, int n_in,
                              void* d_out, int out_size, void* d_ws, size_t ws_size,
                              hipStream_t stream)
{
  const float* items   = (const float*)d_in[0];
  const float* dec_in  = (const float*)d_in[1];
  const float* emb_w   = (const float*)d_in[2];
  const float* emb_b   = (const float*)d_in[3];
  const float* enc_wih = (const float*)d_in[4];
  const float* enc_whh = (const float*)d_in[5];
  const float* enc_bih = (const float*)d_in[6];
  const float* enc_bhh = (const float*)d_in[7];
  const float* dec_wih = (const float*)d_in[8];
  const float* dec_whh = (const float*)d_in[9];
  const float* dec_bih = (const float*)d_in[10];
  const float* dec_bhh = (const float*)d_in[11];
  const float* w3      = (const float*)d_in[14];
  const float* w4      = (const float*)d_in[15];
  const float* v2      = (const float*)d_in[20];
  const float* wori    = (const float*)d_in[23];
  const float* bori    = (const float*)d_in[24];
  float* out = (float*)d_out;

  char* ws = (char*)d_ws;
  size_t off = 0;
  auto alloc = [&](size_t bytes) { size_t o = off; off += (bytes + 255) & ~255UL; return o; };
  float* Wc       = (float*)(ws + alloc(H3_ * IN_ * 4));
  float* bc       = (float*)(ws + alloc(H3_ * 4));
  short* xgb      = (short*)(ws + alloc((size_t)B_ * H3_ * 2));          // 12 MiB
  short* enc_hist = (short*)(ws + alloc((size_t)11 * B_ * H_ * 2));      // 44 MiB
  short* dec_hist = (short*)(ws + alloc((size_t)L_ * B_ * H_ * 2));      // 40 MiB
  short* ew3      = (short*)(ws + alloc((size_t)L_ * B_ * W_ * 2));      // 40 MiB
  short* a4       = (short*)(ws + alloc((size_t)L_ * B_ * W_ * 2));      // 40 MiB
  short* W2e      = (short*)(ws + alloc((size_t)H3_ * H_ * 2));          // 1.5 MiB
  short* W2d      = (short*)(ws + alloc((size_t)H3_ * H_ * 2));          // 1.5 MiB
  short* wih_d    = (short*)(ws + alloc((size_t)H3_ * H_ * 2));
  short* w3b      = (short*)(ws + alloc((size_t)W_ * H_ * 2));
  short* w4b      = (short*)(ws + alloc((size_t)W_ * H_ * 2));
  short* decb     = (short*)(ws + alloc((size_t)B_ * H_ * 2));           // 4 MiB

  // ---- prep ----
  prep_all<<<(425984 + 255) / 256, 256, 0, stream>>>(
      dec_wih, wih_d, w3, w3b, w4, w4b, dec_in, decb);
  prep_w2<<<768, 256, 0, stream>>>(enc_whh, dec_whh, W2e, W2d);
  build_wc<<<384, 256, 0, stream>>>(enc_wih, emb_w, emb_b, enc_bih, Wc, bc);

  hipMemsetAsync(enc_hist, 0, (size_t)B_ * H_ * 2, stream);      // slice 0 = 0

  // xg_dec = dec_in @ dec_wih^T + dec_bih (fixed across decoder steps), bf16
  gemm_bf16<short><<<dim3(12, 32), 256, 0, stream>>>(
      decb, H_, wih_d, H_, dec_bih, xgb, H3_, H_, 1.f);

  // ---- Encoder recurrence: single fused kernel per step (xg inline) ----
  for (int t = 0; t < L_; ++t) {
    gru_fused<true><<<512, 256, 0, stream>>>(
        enc_hist + (size_t)t * B_ * H_, W2e, enc_bhh, nullptr,
        items + (size_t)t * IN_, Wc, bc,
        enc_hist + (size_t)(t + 1) * B_ * H_);
  }

  // ---- Decoder recurrence ----
  for (int t = 0; t < L_; ++t) {
    const short* prev = (t == 0) ? enc_hist + (size_t)10 * B_ * H_
                                 : dec_hist + (size_t)(t - 1) * B_ * H_;
    gru_fused<false><<<512, 256, 0, stream>>>(
        prev, W2d, dec_bhh, xgb, nullptr, nullptr, nullptr,
        dec_hist + (size_t)t * B_ * H_);
  }

  // ---- Merged batched epilogue (ew3/a4 prescaled by LOG2E2) ----
  gemm_epi<<<dim3(4, 320, 2), 256, 0, stream>>>(
      enc_hist + (size_t)B_ * H_, dec_hist, w3b, w4b, ew3, a4);
  out_seq_all<<<B_, 256, 0, stream>>>(ew3, a4, v2, out);
  out_ori_all<<<(B_ * L_) / 4, 256, 0, stream>>>(dec_hist, wori, bori, out);
}

// Round 12
// 519.131 us; speedup vs baseline: 1.1106x; 1.0170x over previous
//
#include <hip/hip_runtime.h>
#include <hip/hip_bf16.h>

// PointerNetwork: B=4096, L=10, IN=8, H=512, W=512. fp32 in/out, ws=256MiB.
// log_softmax over size-1 axes => hi==he==0. Surviving compute:
//   enc GRU, ew3 = h_enc @ w3^T, dec GRU, a4 = h_dec @ w4^T,
//   out_seq = tanh(ew3+a4)@v2, out_ori = h_dec @ wori[:,H:2H]^T + bori.
// Round 18 = R17 with gru_fused's K-loop de-barriered: the FULL A panel
// (64x512 = 64KB) is staged into LDS once in the prologue (vmcnt(6) retires
// all A while B0 stays in flight; ONE barrier), then the 8-iter K-loop has
// zero barriers / zero LDS writes: A read-only shared, B register-dbuf
// (W2 layout, R17-proven), per-iter wait = vmcnt(6) on B only. R17's
// 16 barriers/step -> 1. Chunk swizzle both-sides preserved.

#define B_   4096
#define L_   10
#define IN_  8
#define H_   512
#define H3_  1536
#define W_   512
#define ORI_BASE (B_ * L_ * L_)   // 409600

typedef __attribute__((ext_vector_type(8))) short s8v;
typedef __attribute__((ext_vector_type(4))) short s4v;
typedef __attribute__((ext_vector_type(4))) float f4v;

#define LOG2E  1.4426950408889634f
#define LOG2E2 2.8853900817779268f

__device__ __forceinline__ float sig_fast(float x) {
  float e = __builtin_amdgcn_exp2f(-x * LOG2E);
  return __builtin_amdgcn_rcpf(1.f + e);
}
__device__ __forceinline__ float tanh_fast(float x) {
  float e = __builtin_amdgcn_exp2f(x * LOG2E2);
  return 1.f - 2.f * __builtin_amdgcn_rcpf(e + 1.f);
}
__device__ __forceinline__ short f2bf(float f) {
  __hip_bfloat16 h = __float2bfloat16(f);
  return __builtin_bit_cast(short, h);
}
__device__ __forceinline__ float bf2f(short s) {
  __hip_bfloat16 h = __builtin_bit_cast(__hip_bfloat16, s);
  return __bfloat162float(h);
}
__device__ __forceinline__ void stc(float* p, float v) { *p = v; }
__device__ __forceinline__ void stc(short* p, float v) { *p = f2bf(v); }

// ---- fused prep: fp32->bf16 conversions in one dispatch (4 segments) ----
__global__ __launch_bounds__(256) void prep_all(
    const float* __restrict__ s2, short* __restrict__ d2,   // dec_wih 786432
    const float* __restrict__ s3, short* __restrict__ d3,   // w3      262144
    const float* __restrict__ s4, short* __restrict__ d4,   // w4      262144
    const float* __restrict__ s5, short* __restrict__ d5)   // dec_in  2097152
{
  long i8 = (long)blockIdx.x * 256 + threadIdx.x;   // unit = 8 elements
  const float* s; short* d; long off;
  if      (i8 < 98304)  { s = s2; d = d2; off = i8; }
  else if (i8 < 131072) { s = s3; d = d3; off = i8 - 98304; }
  else if (i8 < 163840) { s = s4; d = d4; off = i8 - 131072; }
  else if (i8 < 425984) { s = s5; d = d5; off = i8 - 163840; }
  else return;
  const float* sp = s + off * 8;
  s8v v;
#pragma unroll
  for (int j = 0; j < 8; ++j) v[j] = f2bf(sp[j]);
  *(s8v*)(d + off * 8) = v;
}

// ---- W2 weight rearrange for register-B gru (proven correct in R9/R17):
// W2[g][c16][kb][hh][lane][8] bf16; lane=(r16,q): element =
// whh[g*512 + c16*16 + r16][kb*64 + hh*32 + q*8 + e]. One 16B chunk/thread.
__global__ __launch_bounds__(256) void prep_w2(
    const float* __restrict__ enc_whh, const float* __restrict__ dec_whh,
    short* __restrict__ W2e, short* __restrict__ W2d)
{
  int tg = blockIdx.x * 256 + threadIdx.x;  // 0..196607
  const float* src = enc_whh; short* dst = W2e;
  int t = tg;
  if (t >= 98304) { t -= 98304; src = dec_whh; dst = W2d; }
  int l = t & 63;
  int u = t >> 6;
  int hh = u & 1, kb = (u >> 1) & 7, c16 = (u >> 4) & 31, g = u >> 9;
  int row = g * 512 + c16 * 16 + (l & 15);
  int colb = kb * 64 + hh * 32 + (l >> 4) * 8;
  const float* sp = src + (long)row * 512 + colb;
  s8v v;
#pragma unroll
  for (int j = 0; j < 8; ++j) v[j] = f2bf(sp[j]);
  *(s8v*)(dst + (long)t * 8) = v;
}

// Fold embedding into encoder input weight. One wave per g-row (1536 waves).
__global__ __launch_bounds__(256) void build_wc(
    const float* __restrict__ enc_wih, const float* __restrict__ emb_w,
    const float* __restrict__ emb_b, const float* __restrict__ enc_bih,
    float* __restrict__ Wc, float* __restrict__ bc)
{
  __shared__ float se[H_ * IN_];   // 16 KB
  __shared__ float sb[H_];         // 2 KB
  const int tid = threadIdx.x;
  for (int i = tid; i < H_ * IN_; i += 256) se[i] = emb_w[i];
  for (int i = tid; i < H_; i += 256) sb[i] = emb_b[i];
  __syncthreads();
  int g = (blockIdx.x * 256 + tid) >> 6;
  int lane = tid & 63;
  const float* wr = enc_wih + (long)g * H_ + lane * 8;
  float w8[8];
#pragma unroll
  for (int j = 0; j < 8; ++j) w8[j] = wr[j];
  float acc[9] = {};
#pragma unroll
  for (int kk = 0; kk < 8; ++kk) {
    int k = lane * 8 + kk;
#pragma unroll
    for (int j = 0; j < 8; ++j) acc[j] += w8[kk] * se[k * IN_ + j];
    acc[8] += w8[kk] * sb[k];
  }
#pragma unroll
  for (int j = 0; j < 9; ++j)
#pragma unroll
    for (int off = 32; off; off >>= 1) acc[j] += __shfl_down(acc[j], off, 64);
  if (lane == 0) {
#pragma unroll
    for (int j = 0; j < 8; ++j) Wc[g * IN_ + j] = acc[j];
    bc[g] = acc[8] + enc_bih[g];
  }
}

// ---- Pipelined bf16 MFMA GEMM: C[M,N] = (A@B^T (+bias))*scale.
// 128x128 tile, BK=64, double-buffered LDS (64KB, 2 blk/CU), counted
// vmcnt(8), XOR-swizzled 16B chunks (both-sides), setprio around MFMA.
template <typename CT>
__global__ __launch_bounds__(256) void gemm_bf16(
    const short* __restrict__ A, long lda,
    const short* __restrict__ Bw, long ldb,
    const float* __restrict__ bias,
    CT* __restrict__ C, long ldc, int K, float scale)
{
  __shared__ short As[2][128 * 64];   // 32 KB
  __shared__ short Bs[2][128 * 64];   // 32 KB
  const int tid = threadIdx.x;
  const long row0 = (long)blockIdx.y * 128;
  const long col0 = (long)blockIdx.x * 128;
  const int wave = tid >> 6, lane = tid & 63;
  const int wm = (wave & 1) * 64, wn = (wave >> 1) * 64;
  const int r16 = lane & 15, quad = lane >> 4;
  const int sw = r16 & 7;
  f4v acc[4][4] = {};

  auto stage = [&](int buf, int k0) {
#pragma unroll
    for (int r = 0; r < 4; ++r) {             // A: 128x64 = 1024 chunks
      int idx = r * 256 + tid;
      int m = idx >> 3, c8 = idx & 7;
      int src = c8 ^ (m & 7);
      __builtin_amdgcn_global_load_lds(
          (const __attribute__((address_space(1))) void*)(A + (row0 + m) * lda + k0 + src * 8),
          (__attribute__((address_space(3))) void*)(&As[buf][idx * 8]), 16, 0, 0);
    }
#pragma unroll
    for (int r = 0; r < 4; ++r) {             // B: 128x64 = 1024 chunks
      int idx = r * 256 + tid;
      int m = idx >> 3, c8 = idx & 7;
      int src = c8 ^ (m & 7);
      __builtin_amdgcn_global_load_lds(
          (const __attribute__((address_space(1))) void*)(Bw + (col0 + m) * ldb + k0 + src * 8),
          (__attribute__((address_space(3))) void*)(&Bs[buf][idx * 8]), 16, 0, 0);
    }
  };

  const int nk = K >> 6;
  stage(0, 0);
  for (int k = 0; k < nk; ++k) {
    if (k < nk - 1) {
      stage((k + 1) & 1, (k + 1) * 64);
      asm volatile("s_waitcnt vmcnt(8)" ::: "memory");   // cur's 8 loads done
    } else {
      asm volatile("s_waitcnt vmcnt(0)" ::: "memory");
    }
    __builtin_amdgcn_s_barrier();
    const short* Asc = As[k & 1];
    const short* Bsc = Bs[k & 1];
    s8v af[4][2], bf[4][2];
#pragma unroll
    for (int i = 0; i < 4; ++i)
#pragma unroll
      for (int hh = 0; hh < 2; ++hh)
        af[i][hh] = *(const s8v*)&Asc[(wm + i * 16 + r16) * 64 + ((hh * 4 + quad) ^ sw) * 8];
#pragma unroll
    for (int j = 0; j < 4; ++j)
#pragma unroll
      for (int hh = 0; hh < 2; ++hh)
        bf[j][hh] = *(const s8v*)&Bsc[(wn + j * 16 + r16) * 64 + ((hh * 4 + quad) ^ sw) * 8];
    __builtin_amdgcn_s_setprio(1);
#pragma unroll
    for (int hh = 0; hh < 2; ++hh)
#pragma unroll
      for (int i = 0; i < 4; ++i)
#pragma unroll
        for (int j = 0; j < 4; ++j)
          acc[i][j] = __builtin_amdgcn_mfma_f32_16x16x32_bf16(af[i][hh], bf[j][hh], acc[i][j], 0, 0, 0);
    __builtin_amdgcn_s_setprio(0);
    __builtin_amdgcn_s_barrier();
  }

#pragma unroll
  for (int i = 0; i < 4; ++i) {
    long rbase = row0 + wm + i * 16 + quad * 4;
#pragma unroll
    for (int j = 0; j < 4; ++j) {
      long c = col0 + wn + j * 16 + r16;
      float bv = bias ? bias[c] : 0.f;
#pragma unroll
      for (int rg = 0; rg < 4; ++rg)
        stc(&C[(rbase + rg) * ldc + c], (acc[i][j][rg] + bv) * scale);
    }
  }
}

// ---- Merged epilogue GEMM: z=0 -> ew3 = enc_hist@w3^T; z=1 -> a4 =
// dec_hist@w4^T. Same pipelined body, output *LOG2E2 as bf16.
__global__ __launch_bounds__(256) void gemm_epi(
    const short* __restrict__ Ae, const short* __restrict__ Ad,
    const short* __restrict__ w3b, const short* __restrict__ w4b,
    short* __restrict__ Ce, short* __restrict__ Cd)
{
  const short* A  = blockIdx.z ? Ad : Ae;
  const short* Bw = blockIdx.z ? w4b : w3b;
  short* C        = blockIdx.z ? Cd : Ce;
  __shared__ short As[2][128 * 64];
  __shared__ short Bs[2][128 * 64];
  const int tid = threadIdx.x;
  const long row0 = (long)blockIdx.y * 128;
  const long col0 = (long)blockIdx.x * 128;
  const int wave = tid >> 6, lane = tid & 63;
  const int wm = (wave & 1) * 64, wn = (wave >> 1) * 64;
  const int r16 = lane & 15, quad = lane >> 4;
  const int sw = r16 & 7;
  f4v acc[4][4] = {};

  auto stage = [&](int buf, int k0) {
#pragma unroll
    for (int r = 0; r < 4; ++r) {
      int idx = r * 256 + tid;
      int m = idx >> 3, c8 = idx & 7;
      int src = c8 ^ (m & 7);
      __builtin_amdgcn_global_load_lds(
          (const __attribute__((address_space(1))) void*)(A + (row0 + m) * H_ + k0 + src * 8),
          (__attribute__((address_space(3))) void*)(&As[buf][idx * 8]), 16, 0, 0);
    }
#pragma unroll
    for (int r = 0; r < 4; ++r) {
      int idx = r * 256 + tid;
      int m = idx >> 3, c8 = idx & 7;
      int src = c8 ^ (m & 7);
      __builtin_amdgcn_global_load_lds(
          (const __attribute__((address_space(1))) void*)(Bw + (col0 + m) * H_ + k0 + src * 8),
          (__attribute__((address_space(3))) void*)(&Bs[buf][idx * 8]), 16, 0, 0);
    }
  };

  stage(0, 0);
  for (int k = 0; k < 8; ++k) {
    if (k < 7) {
      stage((k + 1) & 1, (k + 1) * 64);
      asm volatile("s_waitcnt vmcnt(8)" ::: "memory");
    } else {
      asm volatile("s_waitcnt vmcnt(0)" ::: "memory");
    }
    __builtin_amdgcn_s_barrier();
    const short* Asc = As[k & 1];
    const short* Bsc = Bs[k & 1];
    s8v af[4][2], bf[4][2];
#pragma unroll
    for (int i = 0; i < 4; ++i)
#pragma unroll
      for (int hh = 0; hh < 2; ++hh)
        af[i][hh] = *(const s8v*)&Asc[(wm + i * 16 + r16) * 64 + ((hh * 4 + quad) ^ sw) * 8];
#pragma unroll
    for (int j = 0; j < 4; ++j)
#pragma unroll
      for (int hh = 0; hh < 2; ++hh)
        bf[j][hh] = *(const s8v*)&Bsc[(wn + j * 16 + r16) * 64 + ((hh * 4 + quad) ^ sw) * 8];
    __builtin_amdgcn_s_setprio(1);
#pragma unroll
    for (int hh = 0; hh < 2; ++hh)
#pragma unroll
      for (int i = 0; i < 4; ++i)
#pragma unroll
        for (int j = 0; j < 4; ++j)
          acc[i][j] = __builtin_amdgcn_mfma_f32_16x16x32_bf16(af[i][hh], bf[j][hh], acc[i][j], 0, 0, 0);
    __builtin_amdgcn_s_setprio(0);
    __builtin_amdgcn_s_barrier();
  }

#pragma unroll
  for (int i = 0; i < 4; ++i) {
    long rbase = row0 + wm + i * 16 + quad * 4;
#pragma unroll
    for (int j = 0; j < 4; ++j) {
      long c = col0 + wn + j * 16 + r16;
#pragma unroll
      for (int rg = 0; rg < 4; ++rg)
        C[(rbase + rg) * W_ + c] = f2bf(acc[i][j][rg] * LOG2E2);
    }
  }
}

// ---- Fused GRU step, Round-18: full-A-in-LDS, barrier-free K-loop.
// Tile: 64 rows x 64 cols x 3 gates. Flat grid 512, 256 thr (4 waves,
// c16 = bx*4+wave). by=flat&63, bx=flat>>6 (row-panel sharers same-XCD).
// Prologue: stage ALL of A (64x512 = 64KB, 16 chunks/thread, chunk-swizzled
// c^=(m&7)), issue B0, vmcnt(6) (retires all A, B0 in flight), ONE barrier.
// K-loop: {loadB(k+1); vmcnt(6); 24 MFMA} -- no barriers, no LDS writes.
template <bool ENC>
__global__ __launch_bounds__(256) void gru_fused(
    const short* __restrict__ Aprev,  // (B,H) bf16 h_{t-1}
    const short* __restrict__ W2,     // rearranged weights (prep_w2)
    const float* __restrict__ bhh,    // (3H)
    const short* __restrict__ xg,     // (B,3H) bf16 (decoder)
    const float* __restrict__ items_t,// encoder: &items[0][t][0], row stride 80
    const float* __restrict__ Wc,     // (3H,8)
    const float* __restrict__ bc,     // (3H)
    short* __restrict__ hout)         // (B,H) bf16 history slice
{
  __shared__ short As[64 * 512];      // 64 KB, full A panel
  const int tid = threadIdx.x;
  const int flat = blockIdx.x;
  const int by = flat & 63, bx = flat >> 6;   // XCD row-panel swizzle
  const long row0 = (long)by * 64;
  const int col0 = bx * 64;
  const int wave = tid >> 6, lane = tid & 63;
  const int r16 = lane & 15, quad = lane >> 4;
  const int sw = r16 & 7;
  const int c16 = bx * 4 + wave;
  const int col = col0 + wave * 16 + r16;

  f4v acc[3][4] = {};   // [gate][frag-row]
  s8v bfr[2][3][2];     // register B double-buffer

  auto loadB = [&](s8v (&dst)[3][2], int kb) {
#pragma unroll
    for (int g = 0; g < 3; ++g)
#pragma unroll
      for (int hh = 0; hh < 2; ++hh)
        dst[g][hh] = *(const s8v*)(W2 + ((((long)(g * 32 + c16) * 8 + kb) * 2 + hh) * 512) + lane * 8);
  };

  // ---- prologue: stage full A panel (4096 chunks, 16/thread), B0 ----
#pragma unroll
  for (int r = 0; r < 16; ++r) {
    int idx = r * 256 + tid;
    int m = idx >> 6, c = idx & 63;
    int src = c ^ (m & 7);            // XORs low-3 bits only
    __builtin_amdgcn_global_load_lds(
        (const __attribute__((address_space(1))) void*)(Aprev + (row0 + m) * H_ + src * 8),
        (__attribute__((address_space(3))) void*)(&As[idx * 8]), 16, 0, 0);
  }
  loadB(bfr[0], 0);                   // 22 outstanding
  asm volatile("s_waitcnt vmcnt(6)" ::: "memory");   // all A retired; B0 in flight
  __builtin_amdgcn_s_barrier();       // A visible to all waves

  // ---- K-loop: no barriers, no LDS writes ----
  for (int k = 0; k < 8; ++k) {
    if (k < 7) {
      loadB(bfr[(k + 1) & 1], k + 1);                 // <=12 outstanding
      asm volatile("s_waitcnt vmcnt(6)" ::: "memory"); // retire B(k)
    } else {
      asm volatile("s_waitcnt vmcnt(0)" ::: "memory");
    }
    s8v af[4][2];
#pragma unroll
    for (int i = 0; i < 4; ++i)
#pragma unroll
      for (int hh = 0; hh < 2; ++hh)
        af[i][hh] = *(const s8v*)&As[(i * 16 + r16) * 512 + k * 64 + ((hh * 4 + quad) ^ sw) * 8];
    __builtin_amdgcn_s_setprio(1);
#pragma unroll
    for (int hh = 0; hh < 2; ++hh)
#pragma unroll
      for (int g = 0; g < 3; ++g)
#pragma unroll
        for (int i = 0; i < 4; ++i)
          acc[g][i] = __builtin_amdgcn_mfma_f32_16x16x32_bf16(af[i][hh], bfr[k & 1][g][hh], acc[g][i], 0, 0, 0);
    __builtin_amdgcn_s_setprio(0);
  }

  // Column owned by this thread (C/D layout: col=lane&15, row=quad*4+reg).
  float wc[3][8], bcv[3];
  if (ENC) {
#pragma unroll
    for (int g = 0; g < 3; ++g) {
      const float* wr = Wc + ((long)g * H_ + col) * IN_;
#pragma unroll
      for (int j = 0; j < 8; ++j) wc[g][j] = wr[j];
      bcv[g] = bc[g * H_ + col];
    }
    // reuse As for items: need all waves past their LDS reads first
    __syncthreads();
    float* itemS = (float*)As;
    int i2 = tid * 2;
    int m = i2 >> 3, j = i2 & 7;
    itemS[i2] = items_t[(row0 + m) * (L_ * IN_) + j];
    itemS[i2 + 1] = items_t[(row0 + m) * (L_ * IN_) + j + 1];
    __syncthreads();
  }
  float bhr = bhh[col], bhz = bhh[col + H_], bhn = bhh[col + 2 * H_];

#pragma unroll
  for (int i = 0; i < 4; ++i) {
#pragma unroll
    for (int rg = 0; rg < 4; ++rg) {
      int rl = i * 16 + quad * 4 + rg;
      long row = row0 + rl;
      float xr, xz, xn;
      if (ENC) {
        const float* it = (const float*)As + rl * 8;
        xr = bcv[0]; xz = bcv[1]; xn = bcv[2];
#pragma unroll
        for (int j = 0; j < 8; ++j) {
          float iv = it[j];
          xr += iv * wc[0][j];
          xz += iv * wc[1][j];
          xn += iv * wc[2][j];
        }
      } else {
        long gx = row * H3_ + col;
        xr = bf2f(xg[gx]); xz = bf2f(xg[gx + H_]); xn = bf2f(xg[gx + 2 * H_]);
      }
      float r = sig_fast(xr + acc[0][i][rg] + bhr);
      float z = sig_fast(xz + acc[1][i][rg] + bhz);
      float n = tanh_fast(xn + r * (acc[2][i][rg] + bhn));
      long hi = row * H_ + col;
      float hp = bf2f(Aprev[hi]);                 // bf16 h_{t-1} (L2-hot)
      float hv = (1.f - z) * n + z * hp;
      hout[hi] = f2bf(hv);
    }
  }
}

// ---- out_seq via MFMA dot (R10 proven): one block per b, 256 thr.
__global__ __launch_bounds__(256) void out_seq_all(
    const short* __restrict__ ew3,   // (Lenc, B, W) bf16, prescaled
    const short* __restrict__ a4,    // (Ldec, B, W) bf16, prescaled
    const float* __restrict__ v2,
    float* __restrict__ out)
{
  __shared__ short s_e[L_ * W_];        // 10 KB
  __shared__ short s_a[L_ * W_];        // 10 KB
  __shared__ short v2b[W_];             // 1 KB
  __shared__ float part[7 * 4 * 4 * 4]; // [g][quad][w][rg]
  __shared__ float svtot_s;
  const int b = blockIdx.x;
  const int tid = threadIdx.x;
  const int w = tid >> 6, lane = tid & 63;
  const int r16 = lane & 15, quad = lane >> 4;

  for (int i = tid; i < L_ * 64; i += 256) {
    int row = i >> 6, c = i & 63;
    int swc = (c ^ (row & 7)) * 8;
    *(s8v*)(s_e + row * W_ + swc) = *(const s8v*)(ew3 + ((long)row * B_ + b) * W_ + c * 8);
    *(s8v*)(s_a + row * W_ + swc) = *(const s8v*)(a4  + ((long)row * B_ + b) * W_ + c * 8);
  }
  {
    int i = tid * 2;
    v2b[i] = f2bf(v2[i]);
    v2b[i + 1] = f2bf(v2[i + 1]);
  }
  if (w == 0) {   // svtot = sum(v2)
    float s = 0.f;
    const float* vp = v2 + lane * 8;
#pragma unroll
    for (int j = 0; j < 8; ++j) s += vp[j];
#pragma unroll
    for (int off = 32; off; off >>= 1) s += __shfl_down(s, off, 64);
    if (lane == 0) svtot_s = s;
  }
  __syncthreads();

  s8v vfrag[4];
#pragma unroll
  for (int j = 0; j < 4; ++j)
    vfrag[j] = *(const s8v*)(v2b + (w * 4 + j) * 32 + quad * 8);

  f4v acc[7] = {};
#pragma unroll
  for (int g = 0; g < 7; ++g) {
    int p = g * 16 + r16;
    int t = (p * 205) >> 11;          // p/10 (valid p<1028)
    int l = p - t * 10;
    if (t > 9) t = 9;                 // dead slots p>=100: clamp, discard later
    const short* ep = s_e + l * W_;
    const short* ap = s_a + t * W_;
    const int le = l & 7, ta = t & 7;
#pragma unroll
    for (int j = 0; j < 4; ++j) {
      int cb = (w * 4 + j) * 4 + quad;
      s8v ev = *(const s8v*)(ep + (cb ^ le) * 8);
      s8v av = *(const s8v*)(ap + (cb ^ ta) * 8);
      s8v sf;
#pragma unroll
      for (int e = 0; e < 8; ++e) {
        float x = bf2f(ev[e]) + bf2f(av[e]);   // already *LOG2E2
        float s = __builtin_amdgcn_rcpf(__builtin_amdgcn_exp2f(x) + 1.f);
        sf[e] = f2bf(s);
      }
      acc[g] = __builtin_amdgcn_mfma_f32_16x16x32_bf16(sf, vfrag[j], acc[g], 0, 0, 0);
    }
  }

  if (r16 == 0) {
#pragma unroll
    for (int g = 0; g < 7; ++g)
      *(f4v*)(part + ((g * 4 + quad) * 4 + w) * 4) = acc[g];
  }
  __syncthreads();
  if (tid < 112) {
    int g = tid >> 4, row = tid & 15;
    int q = row >> 2, rg = row & 3;
    float s = 0.f;
#pragma unroll
    for (int ww = 0; ww < 4; ++ww)
      s += part[((g * 4 + q) * 4 + ww) * 4 + rg];
    int p = g * 16 + row;
    if (p < 100) {
      int t = (p * 205) >> 11;
      int l = p - t * 10;
      out[((long)b * L_ + t) * L_ + l] = svtot_s - 2.f * s;
    }
  }
}

// ---- batched out_ori: one wave per (b,t). ----
__global__ __launch_bounds__(256) void out_ori_all(
    const short* __restrict__ dh,    // (Ldec, B, H) bf16
    const float* __restrict__ wori, const float* __restrict__ bori,
    float* __restrict__ out)
{
  int wid = (blockIdx.x * 256 + threadIdx.x) >> 6;   // b*L + t
  int lane = threadIdx.x & 63;
  int b = wid / L_, t = wid - b * L_;
  s8v hv = *(const s8v*)(dh + ((long)t * B_ + b) * H_ + lane * 8);
  float hf[8];
#pragma unroll
  for (int j = 0; j < 8; ++j) hf[j] = bf2f(hv[j]);
  float res[6];
#pragma unroll
  for (int o = 0; o < 6; ++o) {
    const float* wr = wori + (long)o * H3_ + H_ + lane * 8;
    float acc = 0.f;
#pragma unroll
    for (int j = 0; j < 8; ++j) acc += hf[j] * wr[j];
#pragma unroll
    for (int off = 32; off; off >>= 1) acc += __shfl_down(acc, off, 64);
    res[o] = acc;
  }
  if (lane == 0) {
    float* po = out + ORI_BASE + ((long)b * L_ + t) * 6;
#pragma unroll
    for (int o = 0; o < 6; ++o) po[o] = res[o] + bori[o];
  }
}

extern "C" void kernel_launch(void* const* d_in, const int* in_sizes, int n_in,
                              void* d_out, int out_size, void* d_ws, size_t ws_size,
                              hipStream_t stream)
{
  const float* items   = (const float*)d_in[0];
  const float* dec_in  = (const float*)d_in[1];
  const float* emb_w   = (const float*)d_in[2];
  const float* emb_b   = (const float*)d_in[3];
  const float* enc_wih = (const float*)d_in[4];
  const float* enc_whh = (const float*)d_in[5];
  const float* enc_bih = (const float*)d_in[6];
  const float* enc_bhh = (const float*)d_in[7];
  const float* dec_wih = (const float*)d_in[8];
  const float* dec_whh = (const float*)d_in[9];
  const float* dec_bih = (const float*)d_in[10];
  const float* dec_bhh = (const float*)d_in[11];
  const float* w3      = (const float*)d_in[14];
  const float* w4      = (const float*)d_in[15];
  const float* v2      = (const float*)d_in[20];
  const float* wori    = (const float*)d_in[23];
  const float* bori    = (const float*)d_in[24];
  float* out = (float*)d_out;

  char* ws = (char*)d_ws;
  size_t off = 0;
  auto alloc = [&](size_t bytes) { size_t o = off; off += (bytes + 255) & ~255UL; return o; };
  float* Wc       = (float*)(ws + alloc(H3_ * IN_ * 4));
  float* bc       = (float*)(ws + alloc(H3_ * 4));
  short* xgb      = (short*)(ws + alloc((size_t)B_ * H3_ * 2));          // 12 MiB
  short* enc_hist = (short*)(ws + alloc((size_t)11 * B_ * H_ * 2));      // 44 MiB
  short* dec_hist = (short*)(ws + alloc((size_t)L_ * B_ * H_ * 2));      // 40 MiB
  short* ew3      = (short*)(ws + alloc((size_t)L_ * B_ * W_ * 2));      // 40 MiB
  short* a4       = (short*)(ws + alloc((size_t)L_ * B_ * W_ * 2));      // 40 MiB
  short* W2e      = (short*)(ws + alloc((size_t)H3_ * H_ * 2));          // 1.5 MiB
  short* W2d      = (short*)(ws + alloc((size_t)H3_ * H_ * 2));          // 1.5 MiB
  short* wih_d    = (short*)(ws + alloc((size_t)H3_ * H_ * 2));
  short* w3b      = (short*)(ws + alloc((size_t)W_ * H_ * 2));
  short* w4b      = (short*)(ws + alloc((size_t)W_ * H_ * 2));
  short* decb     = (short*)(ws + alloc((size_t)B_ * H_ * 2));           // 4 MiB

  // ---- prep ----
  prep_all<<<(425984 + 255) / 256, 256, 0, stream>>>(
      dec_wih, wih_d, w3, w3b, w4, w4b, dec_in, decb);
  prep_w2<<<768, 256, 0, stream>>>(enc_whh, dec_whh, W2e, W2d);
  build_wc<<<384, 256, 0, stream>>>(enc_wih, emb_w, emb_b, enc_bih, Wc, bc);

  hipMemsetAsync(enc_hist, 0, (size_t)B_ * H_ * 2, stream);      // slice 0 = 0

  // xg_dec = dec_in @ dec_wih^T + dec_bih (fixed across decoder steps), bf16
  gemm_bf16<short><<<dim3(12, 32), 256, 0, stream>>>(
      decb, H_, wih_d, H_, dec_bih, xgb, H3_, H_, 1.f);

  // ---- Encoder recurrence: single fused kernel per step (xg inline) ----
  for (int t = 0; t < L_; ++t) {
    gru_fused<true><<<512, 256, 0, stream>>>(
        enc_hist + (size_t)t * B_ * H_, W2e, enc_bhh, nullptr,
        items + (size_t)t * IN_, Wc, bc,
        enc_hist + (size_t)(t + 1) * B_ * H_);
  }

  // ---- Decoder recurrence ----
  for (int t = 0; t < L_; ++t) {
    const short* prev = (t == 0) ? enc_hist + (size_t)10 * B_ * H_
                                 : dec_hist + (size_t)(t - 1) * B_ * H_;
    gru_fused<false><<<512, 256, 0, stream>>>(
        prev, W2d, dec_bhh, xgb, nullptr, nullptr, nullptr,
        dec_hist + (size_t)t * B_ * H_);
  }

  // ---- Merged batched epilogue (ew3/a4 prescaled by LOG2E2) ----
  gemm_epi<<<dim3(4, 320, 2), 256, 0, stream>>>(
      enc_hist + (size_t)B_ * H_, dec_hist, w3b, w4b, ew3, a4);
  out_seq_all<<<B_, 256, 0, stream>>>(ew3, a4, v2, out);
  out_ori_all<<<(B_ * L_) / 4, 256, 0, stream>>>(dec_hist, wori, bori, out);
}